// Round 13
// baseline (421.685 us; speedup 1.0000x reference)
//
#include <hip/hip_runtime.h>
#include <hip/hip_bf16.h>
#include <cstdint>
#include <cstddef>

typedef __attribute__((ext_vector_type(8))) short short8;
typedef __attribute__((ext_vector_type(4))) float f32x4;
typedef __attribute__((ext_vector_type(4))) unsigned uint4v;

#define LDS_AS __attribute__((address_space(3)))
#define GLB_AS __attribute__((address_space(1)))

__device__ __forceinline__ unsigned short f32_bf16(float f) {
  unsigned u = __builtin_bit_cast(unsigned, f);
  u += 0x7fffu + ((u >> 16) & 1u);
  return (unsigned short)(u >> 16);
}

__device__ __forceinline__ unsigned cvt_pk_bf16(float lo, float hi) {
  unsigned r;
  asm("v_cvt_pk_bf16_f32 %0, %1, %2" : "=v"(r) : "v"(lo), "v"(hi));
  return r;
}

// ---------------- convert f32 -> bf16, 4 elems/thread ----------------
__global__ __launch_bounds__(256) void k_cvt(const float* __restrict__ in,
                                             unsigned short* __restrict__ out, int n4) {
  int i = blockIdx.x * 256 + threadIdx.x;
  if (i >= n4) return;
  float4 v = reinterpret_cast<const float4*>(in)[i];
  ushort4 o;
  o.x = f32_bf16(v.x); o.y = f32_bf16(v.y); o.z = f32_bf16(v.z); o.w = f32_bf16(v.w);
  reinterpret_cast<ushort4*>(out)[i] = o;
}

// ---------- convert + transpose: in (R x C) f32 -> out (C x R) bf16 ----------
__global__ __launch_bounds__(256) void k_cvt_t(const float* __restrict__ in,
                                               unsigned short* __restrict__ out,
                                               int R, int C) {
  __shared__ float t[32][33];
  int c0 = blockIdx.x * 32, r0 = blockIdx.y * 32;
  int lr = threadIdx.x & 31, lw = threadIdx.x >> 5;
#pragma unroll
  for (int i = 0; i < 32; i += 8)
    t[lw + i][lr] = in[(size_t)(r0 + lw + i) * C + c0 + lr];
  __syncthreads();
#pragma unroll
  for (int i = 0; i < 32; i += 8)
    out[(size_t)(c0 + lw + i) * R + r0 + lr] = f32_bf16(t[lr][lw + i]);
}

// ---------------- shared GEMM-BT mainloop (C = A * Bt^T) ----------------
__device__ __forceinline__ void gemm_bt_mainloop(
    const unsigned short* __restrict__ A, const unsigned short* __restrict__ Bt,
    int K, int m0, int n0, unsigned short* lds, int tid, f32x4 acc[4][4]) {
  const int w = tid >> 6, l = tid & 63;
  const int wr = w >> 1, wc = w & 1;
  const int lr = l & 15, lg = l >> 4;
  unsigned short* As = lds;         // [128][32]
  unsigned short* Bs = lds + 4096;  // [128][32]
  for (int kt = 0; kt < K; kt += 32) {
    __syncthreads();
#pragma unroll
    for (int i = 0; i < 2; ++i) {
      int idx = i * 256 + tid;
      const unsigned short* g = A + (size_t)(m0 + (idx >> 2)) * K + kt + (idx & 3) * 8;
      __builtin_amdgcn_global_load_lds((const GLB_AS unsigned int*)g,
          (LDS_AS unsigned int*)(As + (size_t)(i * 256 + w * 64) * 8), 16, 0, 0);
    }
#pragma unroll
    for (int i = 0; i < 2; ++i) {
      int idx = i * 256 + tid;
      const unsigned short* g = Bt + (size_t)(n0 + (idx >> 2)) * K + kt + (idx & 3) * 8;
      __builtin_amdgcn_global_load_lds((const GLB_AS unsigned int*)g,
          (LDS_AS unsigned int*)(Bs + (size_t)(i * 256 + w * 64) * 8), 16, 0, 0);
    }
    __syncthreads();
    short8 a[4], b[4];
#pragma unroll
    for (int m = 0; m < 4; ++m)
      a[m] = *reinterpret_cast<const short8*>(As + (wr * 64 + m * 16 + lr) * 32 + lg * 8);
#pragma unroll
    for (int n = 0; n < 4; ++n)
      b[n] = *reinterpret_cast<const short8*>(Bs + (wc * 64 + n * 16 + lr) * 32 + lg * 8);
#pragma unroll
    for (int m = 0; m < 4; ++m)
#pragma unroll
      for (int n = 0; n < 4; ++n)
        acc[m][n] = __builtin_amdgcn_mfma_f32_16x16x32_bf16(a[m], b[n], acc[m][n], 0, 0, 0);
  }
}

// ---------------- GEMM1: Zb(8192x1024) @ Wqkvt(3072x1024)^T -> Q,K,Vt ----------------
__global__ __launch_bounds__(256) void k_gemm_qkv(
    const unsigned short* __restrict__ Zb, const unsigned short* __restrict__ Wt,
    unsigned short* __restrict__ Qb, unsigned short* __restrict__ Kb,
    unsigned short* __restrict__ Vt) {
  __shared__ unsigned short lds[8192];
  f32x4 acc[4][4];
#pragma unroll
  for (int m = 0; m < 4; ++m)
#pragma unroll
    for (int n = 0; n < 4; ++n) acc[m][n] = (f32x4){0.f, 0.f, 0.f, 0.f};
  const int m0 = blockIdx.x * 128, n0 = blockIdx.y * 128;
  gemm_bt_mainloop(Zb, Wt, 1024, m0, n0, lds, threadIdx.x, acc);
  const int tid = threadIdx.x, w = tid >> 6, l = tid & 63;
  const int wr = w >> 1, wc = w & 1, lr = l & 15, lg = l >> 4;
#pragma unroll
  for (int n = 0; n < 4; ++n) {
    int gc = n0 + wc * 64 + n * 16;
    int part = gc >> 10;
    int within = gc & 1023;
    int h = within >> 6;
    int dhb = (within & 63) + lr;
#pragma unroll
    for (int m = 0; m < 4; ++m) {
      int gr = m0 + wr * 64 + m * 16 + lg * 4;
      int b = gr >> 11, pos = gr & 2047;
      size_t bh = (size_t)(b * 16 + h);
      if (part == 0) {
        unsigned short* dst = Qb + bh * (2048 * 64) + (size_t)pos * 64 + dhb;
#pragma unroll
        for (int r = 0; r < 4; ++r) dst[r * 64] = f32_bf16(acc[m][n][r]);
      } else if (part == 1) {
        unsigned short* dst = Kb + bh * (2048 * 64) + (size_t)pos * 64 + dhb;
#pragma unroll
        for (int r = 0; r < 4; ++r) dst[r * 64] = f32_bf16(acc[m][n][r]);
      } else {
        unsigned short* dst = Vt + bh * (64 * 2048) + (size_t)dhb * 2048 + pos;
        ushort4 pv;
        pv.x = f32_bf16(acc[m][n][0]); pv.y = f32_bf16(acc[m][n][1]);
        pv.z = f32_bf16(acc[m][n][2]); pv.w = f32_bf16(acc[m][n][3]);
        *reinterpret_cast<ushort4*>(dst) = pv;
      }
    }
  }
}

// -------- softmax + P-pack for one 16-q group (defer-max THR=8, shuffle l-sum) ----
// Round-10-verified version.
__device__ __forceinline__ void softmax_pack(f32x4 s[4], float& m_r, float& l_r,
                                             f32x4 o[4], short8 pb[2], bool lgodd,
                                             float cc) {
  float t0 = fmaxf(fmaxf(s[0][0], s[0][1]), s[0][2]);
  float t1 = fmaxf(fmaxf(s[0][3], s[1][0]), s[1][1]);
  float t2 = fmaxf(fmaxf(s[1][2], s[1][3]), s[2][0]);
  float t3 = fmaxf(fmaxf(s[2][1], s[2][2]), s[2][3]);
  float t4 = fmaxf(fmaxf(s[3][0], s[3][1]), s[3][2]);
  float tl = fmaxf(fmaxf(fmaxf(t0, t1), fmaxf(t2, t3)), fmaxf(t4, s[3][3]));
  if (__any(tl > m_r + 8.0f)) {  // rare after early tiles
    float tm = fmaxf(tl, __shfl_xor(tl, 16));
    tm = fmaxf(tm, __shfl_xor(tm, 32));
    float mn = fmaxf(m_r, tm);
    float al = __builtin_amdgcn_exp2f((m_r - mn) * cc);
    m_r = mn;
    l_r *= al;
#pragma unroll
    for (int c = 0; c < 4; ++c)
#pragma unroll
      for (int r = 0; r < 4; ++r) o[c][r] *= al;
  }
  float nb = m_r * cc;
  float rs = 0.f;
#pragma unroll
  for (int c = 0; c < 4; ++c)
#pragma unroll
    for (int r = 0; r < 4; ++r) {
      float p = __builtin_amdgcn_exp2f(s[c][r] * cc - nb);
      s[c][r] = p;
      rs += p;
    }
  rs += __shfl_xor(rs, 16);
  rs += __shfl_xor(rs, 32);
  l_r += rs;
  unsigned Ap[4], Bp[4];
#pragma unroll
  for (int c = 0; c < 4; ++c) {
    Ap[c] = cvt_pk_bf16(s[c][0], s[c][1]);
    Bp[c] = cvt_pk_bf16(s[c][2], s[c][3]);
  }
#pragma unroll
  for (int kc = 0; kc < 2; ++kc) {
    unsigned ua = Ap[2 * kc], va = Ap[2 * kc + 1];
    asm("v_permlane32_swap_b32 %0, %1" : "+v"(ua), "+v"(va));
    unsigned uas = (unsigned)__shfl_xor((int)ua, 16);
    unsigned vas = (unsigned)__shfl_xor((int)va, 16);
    unsigned w0 = lgodd ? vas : ua;
    unsigned w2 = lgodd ? va : uas;
    unsigned ub = Bp[2 * kc], vb = Bp[2 * kc + 1];
    asm("v_permlane32_swap_b32 %0, %1" : "+v"(ub), "+v"(vb));
    unsigned ubs = (unsigned)__shfl_xor((int)ub, 16);
    unsigned vbs = (unsigned)__shfl_xor((int)vb, 16);
    unsigned w1 = lgodd ? vbs : ub;
    unsigned w3 = lgodd ? vb : ubs;
    uint4v pw = (uint4v){w0, w1, w2, w3};
    pb[kc] = __builtin_bit_cast(short8, pw);
  }
}

// --- flash attention v6: K-only LDS (16KB), V direct from L2, 8 blocks/CU --------
__global__ __launch_bounds__(256, 8) void k_attn(
    const unsigned short* __restrict__ Q, const unsigned short* __restrict__ Kb,
    const unsigned short* __restrict__ Vt, unsigned short* __restrict__ O) {
  __shared__ unsigned short lds[8192];  // [2][K 4096] shorts = 16 KB
  const int tid = threadIdx.x, w = tid >> 6, l = tid & 63;
  const int lr = l & 15, lg = l >> 4;
  const bool lgodd = (lg & 1) != 0;
  // XCD-aware remap (verified r9): 32 q-blocks of one (b,h) share wg&7 -> same XCD.
  const int wg = blockIdx.x;
  const int xcd = wg & 7, local = wg >> 3;
  const int bh = xcd + ((local >> 5) << 3);
  const int qb = local & 31;
  const unsigned short* Qp = Q + (size_t)bh * (2048 * 64);
  const unsigned short* Kp = Kb + (size_t)bh * (2048 * 64);
  const unsigned short* Vp = Vt + (size_t)bh * (64 * 2048);
  const int q0 = qb * 64 + w * 16;

  short8 aq[2];
#pragma unroll
  for (int kc = 0; kc < 2; ++kc)
    aq[kc] = *reinterpret_cast<const short8*>(
        Qp + (size_t)(q0 + lr) * 64 + kc * 32 + lg * 8);

  float m_r = -3e38f, l_r = 0.f;
  f32x4 o[4];
#pragma unroll
  for (int c = 0; c < 4; ++c) o[c] = (f32x4){0.f, 0.f, 0.f, 0.f};
  const f32x4 zero4 = (f32x4){0.f, 0.f, 0.f, 0.f};
  const float cc = 0.125f * 1.44269504089f;  // SCALE * log2(e)

  // loop-invariant swizzle slots for K reads: row&7 == lr&7
  const int sw0 = (lg ^ (lr & 7)) * 8;
  const int sw1 = ((4 + lg) ^ (lr & 7)) * 8;

  const int srow = tid >> 3, sslot = tid & 7;
#define STAGE_K(bufK, kv0)                                                            \
  {                                                                                   \
    _Pragma("unroll")                                                                 \
    for (int i = 0; i < 2; ++i) {                                                     \
      int row = i * 32 + srow;                                                        \
      int sw = sslot ^ (row & 7);                                                     \
      __builtin_amdgcn_global_load_lds(                                               \
          (const GLB_AS unsigned int*)(Kp + (size_t)((kv0) + row) * 64 + sw * 8),     \
          (LDS_AS unsigned int*)((bufK) + (i * 256 + tid) * 8), 16, 0, 0);            \
    }                                                                                 \
  }

  unsigned short* K0 = lds;
  unsigned short* K1 = lds + 4096;

  STAGE_K(K0, 0);
  __syncthreads();

  for (int t = 0; t < 32; ++t) {
    unsigned short* Ks = (t & 1) ? K1 : K0;
    if (t < 31) {
      unsigned short* Kn = (t & 1) ? K0 : K1;
      STAGE_K(Kn, (t + 1) * 64);
    }
    const int kv0 = t * 64;
    f32x4 s[4];
#pragma unroll
    for (int c = 0; c < 4; ++c) {
      const unsigned short* kb = Ks + c * 1024 + lr * 64;
      short8 ak0 = *reinterpret_cast<const short8*>(kb + sw0);
      short8 ak1 = *reinterpret_cast<const short8*>(kb + sw1);
      s[c] = __builtin_amdgcn_mfma_f32_16x16x32_bf16(ak0, aq[0], zero4, 0, 0, 0);
      s[c] = __builtin_amdgcn_mfma_f32_16x16x32_bf16(ak1, aq[1], s[c], 0, 0, 0);
    }
    short8 pb[2];
    softmax_pack(s, m_r, l_r, o, pb, lgodd, cc);
    // V direct from global (L2-resident per XCD; lanes (lr,lg) cover full 64B lines)
#pragma unroll
    for (int c = 0; c < 4; ++c) {
      const unsigned short* vrow = Vp + (size_t)(c * 16 + lr) * 2048 + kv0;
      short8 av0 = *reinterpret_cast<const short8*>(vrow + lg * 8);
      short8 av1 = *reinterpret_cast<const short8*>(vrow + 32 + lg * 8);
      o[c] = __builtin_amdgcn_mfma_f32_16x16x32_bf16(av0, pb[0], o[c], 0, 0, 0);
      o[c] = __builtin_amdgcn_mfma_f32_16x16x32_bf16(av1, pb[1], o[c], 0, 0, 0);
    }
    __syncthreads();
  }

  const int b = bh >> 4, h = bh & 15;
  const float inv = 1.0f / l_r;
  const size_t row = (size_t)b * 2048 + q0 + lr;
#pragma unroll
  for (int c = 0; c < 4; ++c) {
    ushort4 pv;
    pv.x = f32_bf16(o[c][0] * inv);
    pv.y = f32_bf16(o[c][1] * inv);
    pv.z = f32_bf16(o[c][2] * inv);
    pv.w = f32_bf16(o[c][3] * inv);
    *reinterpret_cast<ushort4*>(
        const_cast<unsigned short*>(O + row * 1024 + h * 64 + c * 16 + lg * 4)) = pv;
  }
#undef STAGE_K
}

// ---------------- GEMM2: Ob(8192x1024) @ Woutt(1024x1024)^T + b -> out f32 ----------------
__global__ __launch_bounds__(256) void k_gemm_out(
    const unsigned short* __restrict__ Ob, const unsigned short* __restrict__ Wt,
    const float* __restrict__ bias, float* __restrict__ out) {
  __shared__ unsigned short lds[8192];
  f32x4 acc[4][4];
#pragma unroll
  for (int m = 0; m < 4; ++m)
#pragma unroll
    for (int n = 0; n < 4; ++n) acc[m][n] = (f32x4){0.f, 0.f, 0.f, 0.f};
  const int m0 = blockIdx.x * 128, n0 = blockIdx.y * 128;
  gemm_bt_mainloop(Ob, Wt, 1024, m0, n0, lds, threadIdx.x, acc);
  const int tid = threadIdx.x, w = tid >> 6, l = tid & 63;
  const int wr = w >> 1, wc = w & 1, lr = l & 15, lg = l >> 4;
#pragma unroll
  for (int n = 0; n < 4; ++n) {
    int gc = n0 + wc * 64 + n * 16 + lr;
    float bo = bias[gc];
#pragma unroll
    for (int m = 0; m < 4; ++m) {
      int gr = m0 + wr * 64 + m * 16 + lg * 4;
#pragma unroll
      for (int r = 0; r < 4; ++r)
        out[(size_t)(gr + r) * 1024 + gc] = acc[m][n][r] + bo;
    }
  }
}

extern "C" void kernel_launch(void* const* d_in, const int* in_sizes, int n_in,
                              void* d_out, int out_size, void* d_ws, size_t ws_size,
                              hipStream_t stream) {
  const float* z     = (const float*)d_in[0];
  const float* w_qkv = (const float*)d_in[1];
  const float* w_out = (const float*)d_in[2];
  const float* b_out = (const float*)d_in[3];
  float* out = (float*)d_out;

  unsigned short* ws = (unsigned short*)d_ws;
  unsigned short* Zb    = ws;              // 8192*1024      (reused as Ob after GEMM1)
  unsigned short* Wqkvt = ws + 8388608;    // 3072*1024
  unsigned short* Woutt = ws + 11534336;   // 1024*1024
  unsigned short* Qb    = ws + 12582912;   // B*H*N*DH
  unsigned short* Kb    = ws + 20971520;
  unsigned short* Vt    = ws + 29360128;
  unsigned short* Ob    = Zb;              // alias: Zb dead after GEMM1 (stream-ordered)

  k_cvt<<<dim3(8192), dim3(256), 0, stream>>>(z, Zb, 2097152);
  k_cvt_t<<<dim3(96, 32), dim3(256), 0, stream>>>(w_qkv, Wqkvt, 1024, 3072);
  k_cvt_t<<<dim3(32, 32), dim3(256), 0, stream>>>(w_out, Woutt, 1024, 1024);
  k_gemm_qkv<<<dim3(64, 24), dim3(256), 0, stream>>>(Zb, Wqkvt, Qb, Kb, Vt);
  k_attn<<<dim3(2048), dim3(256), 0, stream>>>(Qb, Kb, Vt, Ob);
  k_gemm_out<<<dim3(64, 8), dim3(256), 0, stream>>>(Ob, Woutt, b_out, out);
}

// Round 14
// 207.727 us; speedup vs baseline: 2.0300x; 2.0300x over previous
//
#include <hip/hip_runtime.h>
#include <hip/hip_bf16.h>
#include <cstdint>
#include <cstddef>

typedef __attribute__((ext_vector_type(8))) short short8;
typedef __attribute__((ext_vector_type(4))) float f32x4;
typedef __attribute__((ext_vector_type(4))) unsigned uint4v;

#define LDS_AS __attribute__((address_space(3)))
#define GLB_AS __attribute__((address_space(1)))

__device__ __forceinline__ unsigned short f32_bf16(float f) {
  unsigned u = __builtin_bit_cast(unsigned, f);
  u += 0x7fffu + ((u >> 16) & 1u);
  return (unsigned short)(u >> 16);
}

__device__ __forceinline__ unsigned cvt_pk_bf16(float lo, float hi) {
  unsigned r;
  asm("v_cvt_pk_bf16_f32 %0, %1, %2" : "=v"(r) : "v"(lo), "v"(hi));
  return r;
}

// ---------------- convert f32 -> bf16, 4 elems/thread ----------------
__global__ __launch_bounds__(256) void k_cvt(const float* __restrict__ in,
                                             unsigned short* __restrict__ out, int n4) {
  int i = blockIdx.x * 256 + threadIdx.x;
  if (i >= n4) return;
  float4 v = reinterpret_cast<const float4*>(in)[i];
  ushort4 o;
  o.x = f32_bf16(v.x); o.y = f32_bf16(v.y); o.z = f32_bf16(v.z); o.w = f32_bf16(v.w);
  reinterpret_cast<ushort4*>(out)[i] = o;
}

// ---------- convert + transpose: in (R x C) f32 -> out (C x R) bf16 ----------
__global__ __launch_bounds__(256) void k_cvt_t(const float* __restrict__ in,
                                               unsigned short* __restrict__ out,
                                               int R, int C) {
  __shared__ float t[32][33];
  int c0 = blockIdx.x * 32, r0 = blockIdx.y * 32;
  int lr = threadIdx.x & 31, lw = threadIdx.x >> 5;
#pragma unroll
  for (int i = 0; i < 32; i += 8)
    t[lw + i][lr] = in[(size_t)(r0 + lw + i) * C + c0 + lr];
  __syncthreads();
#pragma unroll
  for (int i = 0; i < 32; i += 8)
    out[(size_t)(c0 + lw + i) * R + r0 + lr] = f32_bf16(t[lr][lw + i]);
}

// ------ shared GEMM-BT mainloop (C = A * Bt^T), BK=64, XOR-swizzled LDS ------
// A: M x K row-major bf16, Bt: N x K row-major bf16. 128x128 tile.
// Staging: source chunk sslot^(row&7), linear LDS dest (rule #21 both-sides).
__device__ __forceinline__ void gemm_bt_mainloop(
    const unsigned short* __restrict__ A, const unsigned short* __restrict__ Bt,
    int K, int m0, int n0, unsigned short* lds, int tid, f32x4 acc[4][4]) {
  const int w = tid >> 6, l = tid & 63;
  const int wr = w >> 1, wc = w & 1;
  const int lr = l & 15, lg = l >> 4;
  unsigned short* As = lds;         // [128][64] swizzled
  unsigned short* Bs = lds + 8192;  // [128][64] swizzled
  const int sslot = tid & 7;
  for (int kt = 0; kt < K; kt += 64) {
    __syncthreads();
#pragma unroll
    for (int i = 0; i < 4; ++i) {
      int idx = i * 256 + tid;
      int row = idx >> 3;
      int sw = sslot ^ (row & 7);
      __builtin_amdgcn_global_load_lds(
          (const GLB_AS unsigned int*)(A + (size_t)(m0 + row) * K + kt + sw * 8),
          (LDS_AS unsigned int*)(As + (size_t)idx * 8), 16, 0, 0);
    }
#pragma unroll
    for (int i = 0; i < 4; ++i) {
      int idx = i * 256 + tid;
      int row = idx >> 3;
      int sw = sslot ^ (row & 7);
      __builtin_amdgcn_global_load_lds(
          (const GLB_AS unsigned int*)(Bt + (size_t)(n0 + row) * K + kt + sw * 8),
          (LDS_AS unsigned int*)(Bs + (size_t)idx * 8), 16, 0, 0);
    }
    __syncthreads();
#pragma unroll
    for (int kc = 0; kc < 2; ++kc) {
      const int so = ((kc * 4 + lg) ^ (lr & 7)) * 8;  // frag row&7 == lr&7
      short8 a[4], b[4];
#pragma unroll
      for (int m = 0; m < 4; ++m)
        a[m] = *reinterpret_cast<const short8*>(As + (wr * 64 + m * 16 + lr) * 64 + so);
#pragma unroll
      for (int n = 0; n < 4; ++n)
        b[n] = *reinterpret_cast<const short8*>(Bs + (wc * 64 + n * 16 + lr) * 64 + so);
#pragma unroll
      for (int m = 0; m < 4; ++m)
#pragma unroll
        for (int n = 0; n < 4; ++n)
          acc[m][n] = __builtin_amdgcn_mfma_f32_16x16x32_bf16(a[m], b[n], acc[m][n], 0, 0, 0);
    }
  }
}

// ---------------- GEMM1: Zb(8192x1024) @ Wqkvt(3072x1024)^T -> Q,K,Vt ----------------
__global__ __launch_bounds__(256) void k_gemm_qkv(
    const unsigned short* __restrict__ Zb, const unsigned short* __restrict__ Wt,
    unsigned short* __restrict__ Qb, unsigned short* __restrict__ Kb,
    unsigned short* __restrict__ Vt) {
  __shared__ unsigned short lds[16384];
  f32x4 acc[4][4];
#pragma unroll
  for (int m = 0; m < 4; ++m)
#pragma unroll
    for (int n = 0; n < 4; ++n) acc[m][n] = (f32x4){0.f, 0.f, 0.f, 0.f};
  const int m0 = blockIdx.x * 128, n0 = blockIdx.y * 128;
  gemm_bt_mainloop(Zb, Wt, 1024, m0, n0, lds, threadIdx.x, acc);
  const int tid = threadIdx.x, w = tid >> 6, l = tid & 63;
  const int wr = w >> 1, wc = w & 1, lr = l & 15, lg = l >> 4;
#pragma unroll
  for (int n = 0; n < 4; ++n) {
    int gc = n0 + wc * 64 + n * 16;
    int part = gc >> 10;
    int within = gc & 1023;
    int h = within >> 6;
    int dhb = (within & 63) + lr;
#pragma unroll
    for (int m = 0; m < 4; ++m) {
      int gr = m0 + wr * 64 + m * 16 + lg * 4;
      int b = gr >> 11, pos = gr & 2047;
      size_t bh = (size_t)(b * 16 + h);
      if (part == 0) {
        unsigned short* dst = Qb + bh * (2048 * 64) + (size_t)pos * 64 + dhb;
#pragma unroll
        for (int r = 0; r < 4; ++r) dst[r * 64] = f32_bf16(acc[m][n][r]);
      } else if (part == 1) {
        unsigned short* dst = Kb + bh * (2048 * 64) + (size_t)pos * 64 + dhb;
#pragma unroll
        for (int r = 0; r < 4; ++r) dst[r * 64] = f32_bf16(acc[m][n][r]);
      } else {
        unsigned short* dst = Vt + bh * (64 * 2048) + (size_t)dhb * 2048 + pos;
        ushort4 pv;
        pv.x = f32_bf16(acc[m][n][0]); pv.y = f32_bf16(acc[m][n][1]);
        pv.z = f32_bf16(acc[m][n][2]); pv.w = f32_bf16(acc[m][n][3]);
        *reinterpret_cast<ushort4*>(dst) = pv;
      }
    }
  }
}

// -------- softmax + P-pack for one 16-q group (defer-max THR=8, shuffle l-sum) ----
// Round-10-verified version.
__device__ __forceinline__ void softmax_pack(f32x4 s[4], float& m_r, float& l_r,
                                             f32x4 o[4], short8 pb[2], bool lgodd,
                                             float cc) {
  float t0 = fmaxf(fmaxf(s[0][0], s[0][1]), s[0][2]);
  float t1 = fmaxf(fmaxf(s[0][3], s[1][0]), s[1][1]);
  float t2 = fmaxf(fmaxf(s[1][2], s[1][3]), s[2][0]);
  float t3 = fmaxf(fmaxf(s[2][1], s[2][2]), s[2][3]);
  float t4 = fmaxf(fmaxf(s[3][0], s[3][1]), s[3][2]);
  float tl = fmaxf(fmaxf(fmaxf(t0, t1), fmaxf(t2, t3)), fmaxf(t4, s[3][3]));
  if (__any(tl > m_r + 8.0f)) {  // rare after early tiles
    float tm = fmaxf(tl, __shfl_xor(tl, 16));
    tm = fmaxf(tm, __shfl_xor(tm, 32));
    float mn = fmaxf(m_r, tm);
    float al = __builtin_amdgcn_exp2f((m_r - mn) * cc);
    m_r = mn;
    l_r *= al;
#pragma unroll
    for (int c = 0; c < 4; ++c)
#pragma unroll
      for (int r = 0; r < 4; ++r) o[c][r] *= al;
  }
  float nb = m_r * cc;
  float rs = 0.f;
#pragma unroll
  for (int c = 0; c < 4; ++c)
#pragma unroll
    for (int r = 0; r < 4; ++r) {
      float p = __builtin_amdgcn_exp2f(s[c][r] * cc - nb);
      s[c][r] = p;
      rs += p;
    }
  rs += __shfl_xor(rs, 16);
  rs += __shfl_xor(rs, 32);
  l_r += rs;
  unsigned Ap[4], Bp[4];
#pragma unroll
  for (int c = 0; c < 4; ++c) {
    Ap[c] = cvt_pk_bf16(s[c][0], s[c][1]);
    Bp[c] = cvt_pk_bf16(s[c][2], s[c][3]);
  }
#pragma unroll
  for (int kc = 0; kc < 2; ++kc) {
    unsigned ua = Ap[2 * kc], va = Ap[2 * kc + 1];
    asm("v_permlane32_swap_b32 %0, %1" : "+v"(ua), "+v"(va));
    unsigned uas = (unsigned)__shfl_xor((int)ua, 16);
    unsigned vas = (unsigned)__shfl_xor((int)va, 16);
    unsigned w0 = lgodd ? vas : ua;
    unsigned w2 = lgodd ? va : uas;
    unsigned ub = Bp[2 * kc], vb = Bp[2 * kc + 1];
    asm("v_permlane32_swap_b32 %0, %1" : "+v"(ub), "+v"(vb));
    unsigned ubs = (unsigned)__shfl_xor((int)ub, 16);
    unsigned vbs = (unsigned)__shfl_xor((int)vb, 16);
    unsigned w1 = lgodd ? vbs : ub;
    unsigned w3 = lgodd ? vb : ubs;
    uint4v pw = (uint4v){w0, w1, w2, w3};
    pb[kc] = __builtin_bit_cast(short8, pw);
  }
}

// ------- flash attention (round-10-verified v4a): 128 q/block, K+V LDS dbuf -------
__global__ __launch_bounds__(256, 4) void k_attn(
    const unsigned short* __restrict__ Q, const unsigned short* __restrict__ Kb,
    const unsigned short* __restrict__ Vt, unsigned short* __restrict__ O) {
  __shared__ unsigned short lds[16384];  // [2][K 4096 | V 4096] shorts
  const int tid = threadIdx.x, w = tid >> 6, l = tid & 63;
  const int lr = l & 15, lg = l >> 4;
  const bool lgodd = (lg & 1) != 0;
  // XCD-aware remap (verified r9): 16 q-blocks of one (b,h) share wg&7 -> same XCD.
  const int wg = blockIdx.x;
  const int xcd = wg & 7, local = wg >> 3;
  const int bh = xcd + ((local >> 4) << 3);
  const int qb = local & 15;
  const unsigned short* Qp = Q + (size_t)bh * (2048 * 64);
  const unsigned short* Kp = Kb + (size_t)bh * (2048 * 64);
  const unsigned short* Vp = Vt + (size_t)bh * (64 * 2048);
  const int q0 = qb * 128 + w * 32;

  short8 aq[2][2];
#pragma unroll
  for (int g = 0; g < 2; ++g)
#pragma unroll
    for (int kc = 0; kc < 2; ++kc)
      aq[g][kc] = *reinterpret_cast<const short8*>(
          Qp + (size_t)(q0 + g * 16 + lr) * 64 + kc * 32 + lg * 8);

  float m0r = -3e38f, l0r = 0.f, m1r = -3e38f, l1r = 0.f;
  f32x4 o0[4], o1[4];
#pragma unroll
  for (int c = 0; c < 4; ++c) {
    o0[c] = (f32x4){0.f, 0.f, 0.f, 0.f};
    o1[c] = (f32x4){0.f, 0.f, 0.f, 0.f};
  }
  const float cc = 0.125f * 1.44269504089f;  // SCALE * log2(e)

  const int srow = tid >> 3, sslot = tid & 7;
#define STAGE_KV(bufK, bufV, kv0)                                                     \
  {                                                                                   \
    _Pragma("unroll")                                                                 \
    for (int i = 0; i < 2; ++i) {                                                     \
      int row = i * 32 + srow;                                                        \
      int sw = sslot ^ (row & 7);                                                     \
      __builtin_amdgcn_global_load_lds(                                               \
          (const GLB_AS unsigned int*)(Kp + (size_t)((kv0) + row) * 64 + sw * 8),     \
          (LDS_AS unsigned int*)((bufK) + (i * 256 + tid) * 8), 16, 0, 0);            \
      __builtin_amdgcn_global_load_lds(                                               \
          (const GLB_AS unsigned int*)(Vp + (size_t)row * 2048 + (kv0) + sw * 8),     \
          (LDS_AS unsigned int*)((bufV) + (i * 256 + tid) * 8), 16, 0, 0);            \
    }                                                                                 \
  }

  unsigned short* K0 = lds;
  unsigned short* V0 = lds + 4096;
  unsigned short* K1 = lds + 8192;
  unsigned short* V1 = lds + 12288;

  STAGE_KV(K0, V0, 0);
  __syncthreads();

  for (int t = 0; t < 32; ++t) {
    unsigned short* Ks = (t & 1) ? K1 : K0;
    unsigned short* Vs = (t & 1) ? V1 : V0;
    if (t < 31) {
      unsigned short* Kn = (t & 1) ? K0 : K1;
      unsigned short* Vn = (t & 1) ? V0 : V1;
      STAGE_KV(Kn, Vn, (t + 1) * 64);
    }
    f32x4 s0[4], s1[4];
#pragma unroll
    for (int c = 0; c < 4; ++c) {
      s0[c] = (f32x4){0.f, 0.f, 0.f, 0.f};
      s1[c] = (f32x4){0.f, 0.f, 0.f, 0.f};
    }
#pragma unroll
    for (int c = 0; c < 4; ++c)
#pragma unroll
      for (int kc = 0; kc < 2; ++kc) {
        int row = c * 16 + lr;
        int sw = (kc * 4 + lg) ^ (row & 7);
        short8 ak = *reinterpret_cast<const short8*>(Ks + row * 64 + sw * 8);
        s0[c] = __builtin_amdgcn_mfma_f32_16x16x32_bf16(ak, aq[0][kc], s0[c], 0, 0, 0);
        s1[c] = __builtin_amdgcn_mfma_f32_16x16x32_bf16(ak, aq[1][kc], s1[c], 0, 0, 0);
      }
    short8 pb0[2], pb1[2];
    softmax_pack(s0, m0r, l0r, o0, pb0, lgodd, cc);
    softmax_pack(s1, m1r, l1r, o1, pb1, lgodd, cc);
#pragma unroll
    for (int c = 0; c < 4; ++c)
#pragma unroll
      for (int kc = 0; kc < 2; ++kc) {
        int row = c * 16 + lr;
        int sw = (kc * 4 + lg) ^ (row & 7);
        short8 av = *reinterpret_cast<const short8*>(Vs + row * 64 + sw * 8);
        o0[c] = __builtin_amdgcn_mfma_f32_16x16x32_bf16(av, pb0[kc], o0[c], 0, 0, 0);
        o1[c] = __builtin_amdgcn_mfma_f32_16x16x32_bf16(av, pb1[kc], o1[c], 0, 0, 0);
      }
    __syncthreads();
  }

  const int b = bh >> 4, h = bh & 15;
#pragma unroll
  for (int g = 0; g < 2; ++g) {
    const float inv = 1.0f / (g ? l1r : l0r);
    const f32x4* o = g ? o1 : o0;
    const size_t row = (size_t)b * 2048 + q0 + g * 16 + lr;
#pragma unroll
    for (int c = 0; c < 4; ++c) {
      ushort4 pv;
      pv.x = f32_bf16(o[c][0] * inv);
      pv.y = f32_bf16(o[c][1] * inv);
      pv.z = f32_bf16(o[c][2] * inv);
      pv.w = f32_bf16(o[c][3] * inv);
      *reinterpret_cast<ushort4*>(const_cast<unsigned short*>(
          O + row * 1024 + h * 64 + c * 16 + lg * 4)) = pv;
    }
  }
#undef STAGE_KV
}

// ---------------- GEMM2: Ob(8192x1024) @ Woutt(1024x1024)^T + b -> out f32 ----------------
__global__ __launch_bounds__(256) void k_gemm_out(
    const unsigned short* __restrict__ Ob, const unsigned short* __restrict__ Wt,
    const float* __restrict__ bias, float* __restrict__ out) {
  __shared__ unsigned short lds[16384];
  f32x4 acc[4][4];
#pragma unroll
  for (int m = 0; m < 4; ++m)
#pragma unroll
    for (int n = 0; n < 4; ++n) acc[m][n] = (f32x4){0.f, 0.f, 0.f, 0.f};
  const int m0 = blockIdx.x * 128, n0 = blockIdx.y * 128;
  gemm_bt_mainloop(Ob, Wt, 1024, m0, n0, lds, threadIdx.x, acc);
  const int tid = threadIdx.x, w = tid >> 6, l = tid & 63;
  const int wr = w >> 1, wc = w & 1, lr = l & 15, lg = l >> 4;
#pragma unroll
  for (int n = 0; n < 4; ++n) {
    int gc = n0 + wc * 64 + n * 16 + lr;
    float bo = bias[gc];
#pragma unroll
    for (int m = 0; m < 4; ++m) {
      int gr = m0 + wr * 64 + m * 16 + lg * 4;
#pragma unroll
      for (int r = 0; r < 4; ++r)
        out[(size_t)(gr + r) * 1024 + gc] = acc[m][n][r] + bo;
    }
  }
}

extern "C" void kernel_launch(void* const* d_in, const int* in_sizes, int n_in,
                              void* d_out, int out_size, void* d_ws, size_t ws_size,
                              hipStream_t stream) {
  const float* z     = (const float*)d_in[0];
  const float* w_qkv = (const float*)d_in[1];
  const float* w_out = (const float*)d_in[2];
  const float* b_out = (const float*)d_in[3];
  float* out = (float*)d_out;

  unsigned short* ws = (unsigned short*)d_ws;
  unsigned short* Zb    = ws;              // 8192*1024      (reused as Ob after GEMM1)
  unsigned short* Wqkvt = ws + 8388608;    // 3072*1024
  unsigned short* Woutt = ws + 11534336;   // 1024*1024
  unsigned short* Qb    = ws + 12582912;   // B*H*N*DH
  unsigned short* Kb    = ws + 20971520;
  unsigned short* Vt    = ws + 29360128;
  unsigned short* Ob    = Zb;              // alias: Zb dead after GEMM1 (stream-ordered)

  k_cvt<<<dim3(8192), dim3(256), 0, stream>>>(z, Zb, 2097152);
  k_cvt_t<<<dim3(96, 32), dim3(256), 0, stream>>>(w_qkv, Wqkvt, 1024, 3072);
  k_cvt_t<<<dim3(32, 32), dim3(256), 0, stream>>>(w_out, Woutt, 1024, 1024);
  k_gemm_qkv<<<dim3(64, 24), dim3(256), 0, stream>>>(Zb, Wqkvt, Qb, Kb, Vt);
  k_attn<<<dim3(1024), dim3(256), 0, stream>>>(Qb, Kb, Vt, Ob);
  k_gemm_out<<<dim3(64, 8), dim3(256), 0, stream>>>(Ob, Woutt, b_out, out);
}

// Round 15
// 203.186 us; speedup vs baseline: 2.0754x; 1.0223x over previous
//
#include <hip/hip_runtime.h>
#include <hip/hip_bf16.h>
#include <cstdint>
#include <cstddef>

typedef __attribute__((ext_vector_type(8))) short short8;
typedef __attribute__((ext_vector_type(4))) float f32x4;
typedef __attribute__((ext_vector_type(4))) unsigned uint4v;

#define LDS_AS __attribute__((address_space(3)))
#define GLB_AS __attribute__((address_space(1)))

__device__ __forceinline__ unsigned short f32_bf16(float f) {
  unsigned u = __builtin_bit_cast(unsigned, f);
  u += 0x7fffu + ((u >> 16) & 1u);
  return (unsigned short)(u >> 16);
}

__device__ __forceinline__ unsigned cvt_pk_bf16(float lo, float hi) {
  unsigned r;
  asm("v_cvt_pk_bf16_f32 %0, %1, %2" : "=v"(r) : "v"(lo), "v"(hi));
  return r;
}

// ---------------- convert f32 -> bf16, 4 elems/thread ----------------
__global__ __launch_bounds__(256) void k_cvt(const float* __restrict__ in,
                                             unsigned short* __restrict__ out, int n4) {
  int i = blockIdx.x * 256 + threadIdx.x;
  if (i >= n4) return;
  float4 v = reinterpret_cast<const float4*>(in)[i];
  ushort4 o;
  o.x = f32_bf16(v.x); o.y = f32_bf16(v.y); o.z = f32_bf16(v.z); o.w = f32_bf16(v.w);
  reinterpret_cast<ushort4*>(out)[i] = o;
}

// ---------- convert + transpose: in (R x C) f32 -> out (C x R) bf16 ----------
__global__ __launch_bounds__(256) void k_cvt_t(const float* __restrict__ in,
                                               unsigned short* __restrict__ out,
                                               int R, int C) {
  __shared__ float t[32][33];
  int c0 = blockIdx.x * 32, r0 = blockIdx.y * 32;
  int lr = threadIdx.x & 31, lw = threadIdx.x >> 5;
#pragma unroll
  for (int i = 0; i < 32; i += 8)
    t[lw + i][lr] = in[(size_t)(r0 + lw + i) * C + c0 + lr];
  __syncthreads();
#pragma unroll
  for (int i = 0; i < 32; i += 8)
    out[(size_t)(c0 + lw + i) * R + r0 + lr] = f32_bf16(t[lr][lw + i]);
}

// ------ shared GEMM-BT mainloop (C = A * Bt^T), BK=64, XOR-swizzled LDS ------
// (round-14-verified)
__device__ __forceinline__ void gemm_bt_mainloop(
    const unsigned short* __restrict__ A, const unsigned short* __restrict__ Bt,
    int K, int m0, int n0, unsigned short* lds, int tid, f32x4 acc[4][4]) {
  const int w = tid >> 6, l = tid & 63;
  const int wr = w >> 1, wc = w & 1;
  const int lr = l & 15, lg = l >> 4;
  unsigned short* As = lds;         // [128][64] swizzled
  unsigned short* Bs = lds + 8192;  // [128][64] swizzled
  const int sslot = tid & 7;
  for (int kt = 0; kt < K; kt += 64) {
    __syncthreads();
#pragma unroll
    for (int i = 0; i < 4; ++i) {
      int idx = i * 256 + tid;
      int row = idx >> 3;
      int sw = sslot ^ (row & 7);
      __builtin_amdgcn_global_load_lds(
          (const GLB_AS unsigned int*)(A + (size_t)(m0 + row) * K + kt + sw * 8),
          (LDS_AS unsigned int*)(As + (size_t)idx * 8), 16, 0, 0);
    }
#pragma unroll
    for (int i = 0; i < 4; ++i) {
      int idx = i * 256 + tid;
      int row = idx >> 3;
      int sw = sslot ^ (row & 7);
      __builtin_amdgcn_global_load_lds(
          (const GLB_AS unsigned int*)(Bt + (size_t)(n0 + row) * K + kt + sw * 8),
          (LDS_AS unsigned int*)(Bs + (size_t)idx * 8), 16, 0, 0);
    }
    __syncthreads();
#pragma unroll
    for (int kc = 0; kc < 2; ++kc) {
      const int so = ((kc * 4 + lg) ^ (lr & 7)) * 8;  // frag row&7 == lr&7
      short8 a[4], b[4];
#pragma unroll
      for (int m = 0; m < 4; ++m)
        a[m] = *reinterpret_cast<const short8*>(As + (wr * 64 + m * 16 + lr) * 64 + so);
#pragma unroll
      for (int n = 0; n < 4; ++n)
        b[n] = *reinterpret_cast<const short8*>(Bs + (wc * 64 + n * 16 + lr) * 64 + so);
      __builtin_amdgcn_s_setprio(1);
#pragma unroll
      for (int m = 0; m < 4; ++m)
#pragma unroll
        for (int n = 0; n < 4; ++n)
          acc[m][n] = __builtin_amdgcn_mfma_f32_16x16x32_bf16(a[m], b[n], acc[m][n], 0, 0, 0);
      __builtin_amdgcn_s_setprio(0);
    }
  }
}

// ---------------- GEMM1: Zb(8192x1024) @ Wqkvt(3072x1024)^T -> Q,K,Vt ----------------
__global__ __launch_bounds__(256) void k_gemm_qkv(
    const unsigned short* __restrict__ Zb, const unsigned short* __restrict__ Wt,
    unsigned short* __restrict__ Qb, unsigned short* __restrict__ Kb,
    unsigned short* __restrict__ Vt) {
  __shared__ unsigned short lds[16384];
  f32x4 acc[4][4];
#pragma unroll
  for (int m = 0; m < 4; ++m)
#pragma unroll
    for (int n = 0; n < 4; ++n) acc[m][n] = (f32x4){0.f, 0.f, 0.f, 0.f};
  const int m0 = blockIdx.x * 128, n0 = blockIdx.y * 128;
  gemm_bt_mainloop(Zb, Wt, 1024, m0, n0, lds, threadIdx.x, acc);
  const int tid = threadIdx.x, w = tid >> 6, l = tid & 63;
  const int wr = w >> 1, wc = w & 1, lr = l & 15, lg = l >> 4;
#pragma unroll
  for (int n = 0; n < 4; ++n) {
    int gc = n0 + wc * 64 + n * 16;
    int part = gc >> 10;
    int within = gc & 1023;
    int h = within >> 6;
    int dhb = (within & 63) + lr;
#pragma unroll
    for (int m = 0; m < 4; ++m) {
      int gr = m0 + wr * 64 + m * 16 + lg * 4;
      int b = gr >> 11, pos = gr & 2047;
      size_t bh = (size_t)(b * 16 + h);
      if (part == 0) {
        unsigned short* dst = Qb + bh * (2048 * 64) + (size_t)pos * 64 + dhb;
#pragma unroll
        for (int r = 0; r < 4; ++r) dst[r * 64] = f32_bf16(acc[m][n][r]);
      } else if (part == 1) {
        unsigned short* dst = Kb + bh * (2048 * 64) + (size_t)pos * 64 + dhb;
#pragma unroll
        for (int r = 0; r < 4; ++r) dst[r * 64] = f32_bf16(acc[m][n][r]);
      } else {
        unsigned short* dst = Vt + bh * (64 * 2048) + (size_t)dhb * 2048 + pos;
        ushort4 pv;
        pv.x = f32_bf16(acc[m][n][0]); pv.y = f32_bf16(acc[m][n][1]);
        pv.z = f32_bf16(acc[m][n][2]); pv.w = f32_bf16(acc[m][n][3]);
        *reinterpret_cast<ushort4*>(dst) = pv;
      }
    }
  }
}

// -------- softmax + P-pack for one 16-q group (defer-max THR=8, shuffle l-sum) ----
// Round-10-verified version.
__device__ __forceinline__ void softmax_pack(f32x4 s[4], float& m_r, float& l_r,
                                             f32x4 o[4], short8 pb[2], bool lgodd,
                                             float cc) {
  float t0 = fmaxf(fmaxf(s[0][0], s[0][1]), s[0][2]);
  float t1 = fmaxf(fmaxf(s[0][3], s[1][0]), s[1][1]);
  float t2 = fmaxf(fmaxf(s[1][2], s[1][3]), s[2][0]);
  float t3 = fmaxf(fmaxf(s[2][1], s[2][2]), s[2][3]);
  float t4 = fmaxf(fmaxf(s[3][0], s[3][1]), s[3][2]);
  float tl = fmaxf(fmaxf(fmaxf(t0, t1), fmaxf(t2, t3)), fmaxf(t4, s[3][3]));
  if (__any(tl > m_r + 8.0f)) {  // rare after early tiles
    float tm = fmaxf(tl, __shfl_xor(tl, 16));
    tm = fmaxf(tm, __shfl_xor(tm, 32));
    float mn = fmaxf(m_r, tm);
    float al = __builtin_amdgcn_exp2f((m_r - mn) * cc);
    m_r = mn;
    l_r *= al;
#pragma unroll
    for (int c = 0; c < 4; ++c)
#pragma unroll
      for (int r = 0; r < 4; ++r) o[c][r] *= al;
  }
  float nb = m_r * cc;
  float rs = 0.f;
#pragma unroll
  for (int c = 0; c < 4; ++c)
#pragma unroll
    for (int r = 0; r < 4; ++r) {
      float p = __builtin_amdgcn_exp2f(s[c][r] * cc - nb);
      s[c][r] = p;
      rs += p;
    }
  rs += __shfl_xor(rs, 16);
  rs += __shfl_xor(rs, 32);
  l_r += rs;
  unsigned Ap[4], Bp[4];
#pragma unroll
  for (int c = 0; c < 4; ++c) {
    Ap[c] = cvt_pk_bf16(s[c][0], s[c][1]);
    Bp[c] = cvt_pk_bf16(s[c][2], s[c][3]);
  }
#pragma unroll
  for (int kc = 0; kc < 2; ++kc) {
    unsigned ua = Ap[2 * kc], va = Ap[2 * kc + 1];
    asm("v_permlane32_swap_b32 %0, %1" : "+v"(ua), "+v"(va));
    unsigned uas = (unsigned)__shfl_xor((int)ua, 16);
    unsigned vas = (unsigned)__shfl_xor((int)va, 16);
    unsigned w0 = lgodd ? vas : ua;
    unsigned w2 = lgodd ? va : uas;
    unsigned ub = Bp[2 * kc], vb = Bp[2 * kc + 1];
    asm("v_permlane32_swap_b32 %0, %1" : "+v"(ub), "+v"(vb));
    unsigned ubs = (unsigned)__shfl_xor((int)ub, 16);
    unsigned vbs = (unsigned)__shfl_xor((int)vb, 16);
    unsigned w1 = lgodd ? vbs : ub;
    unsigned w3 = lgodd ? vb : ubs;
    uint4v pw = (uint4v){w0, w1, w2, w3};
    pb[kc] = __builtin_bit_cast(short8, pw);
  }
}

// ------- flash attention v7: round-10 structure + setprio + zero-C + hoisted swz --
__global__ __launch_bounds__(256, 4) void k_attn(
    const unsigned short* __restrict__ Q, const unsigned short* __restrict__ Kb,
    const unsigned short* __restrict__ Vt, unsigned short* __restrict__ O) {
  __shared__ unsigned short lds[16384];  // [2][K 4096 | V 4096] shorts
  const int tid = threadIdx.x, w = tid >> 6, l = tid & 63;
  const int lr = l & 15, lg = l >> 4;
  const bool lgodd = (lg & 1) != 0;
  // XCD-aware remap (verified r9): 16 q-blocks of one (b,h) share wg&7 -> same XCD.
  const int wg = blockIdx.x;
  const int xcd = wg & 7, local = wg >> 3;
  const int bh = xcd + ((local >> 4) << 3);
  const int qb = local & 15;
  const unsigned short* Qp = Q + (size_t)bh * (2048 * 64);
  const unsigned short* Kp = Kb + (size_t)bh * (2048 * 64);
  const unsigned short* Vp = Vt + (size_t)bh * (64 * 2048);
  const int q0 = qb * 128 + w * 32;

  short8 aq[2][2];
#pragma unroll
  for (int g = 0; g < 2; ++g)
#pragma unroll
    for (int kc = 0; kc < 2; ++kc)
      aq[g][kc] = *reinterpret_cast<const short8*>(
          Qp + (size_t)(q0 + g * 16 + lr) * 64 + kc * 32 + lg * 8);

  float m0r = -3e38f, l0r = 0.f, m1r = -3e38f, l1r = 0.f;
  f32x4 o0[4], o1[4];
#pragma unroll
  for (int c = 0; c < 4; ++c) {
    o0[c] = (f32x4){0.f, 0.f, 0.f, 0.f};
    o1[c] = (f32x4){0.f, 0.f, 0.f, 0.f};
  }
  const f32x4 zero4 = (f32x4){0.f, 0.f, 0.f, 0.f};
  const float cc = 0.125f * 1.44269504089f;  // SCALE * log2(e)

  // loop-invariant swizzle offsets: frag row&7 == lr&7 (c*16 = 0 mod 8)
  const int so0 = (lg ^ (lr & 7)) * 8;
  const int so1 = ((4 + lg) ^ (lr & 7)) * 8;

  const int srow = tid >> 3, sslot = tid & 7;
#define STAGE_KV(bufK, bufV, kv0)                                                     \
  {                                                                                   \
    _Pragma("unroll")                                                                 \
    for (int i = 0; i < 2; ++i) {                                                     \
      int row = i * 32 + srow;                                                        \
      int sw = sslot ^ (row & 7);                                                     \
      __builtin_amdgcn_global_load_lds(                                               \
          (const GLB_AS unsigned int*)(Kp + (size_t)((kv0) + row) * 64 + sw * 8),     \
          (LDS_AS unsigned int*)((bufK) + (i * 256 + tid) * 8), 16, 0, 0);            \
      __builtin_amdgcn_global_load_lds(                                               \
          (const GLB_AS unsigned int*)(Vp + (size_t)row * 2048 + (kv0) + sw * 8),     \
          (LDS_AS unsigned int*)((bufV) + (i * 256 + tid) * 8), 16, 0, 0);            \
    }                                                                                 \
  }

  unsigned short* K0 = lds;
  unsigned short* V0 = lds + 4096;
  unsigned short* K1 = lds + 8192;
  unsigned short* V1 = lds + 12288;

  STAGE_KV(K0, V0, 0);
  __syncthreads();

  for (int t = 0; t < 32; ++t) {
    unsigned short* Ks = (t & 1) ? K1 : K0;
    unsigned short* Vs = (t & 1) ? V1 : V0;
    if (t < 31) {
      unsigned short* Kn = (t & 1) ? K0 : K1;
      unsigned short* Vn = (t & 1) ? V0 : V1;
      STAGE_KV(Kn, Vn, (t + 1) * 64);
    }
    f32x4 s0[4], s1[4];
    __builtin_amdgcn_s_setprio(1);
#pragma unroll
    for (int c = 0; c < 4; ++c) {
      const unsigned short* kb = Ks + c * 1024 + lr * 64;
      short8 ak0 = *reinterpret_cast<const short8*>(kb + so0);
      short8 ak1 = *reinterpret_cast<const short8*>(kb + so1);
      s0[c] = __builtin_amdgcn_mfma_f32_16x16x32_bf16(ak0, aq[0][0], zero4, 0, 0, 0);
      s1[c] = __builtin_amdgcn_mfma_f32_16x16x32_bf16(ak0, aq[1][0], zero4, 0, 0, 0);
      s0[c] = __builtin_amdgcn_mfma_f32_16x16x32_bf16(ak1, aq[0][1], s0[c], 0, 0, 0);
      s1[c] = __builtin_amdgcn_mfma_f32_16x16x32_bf16(ak1, aq[1][1], s1[c], 0, 0, 0);
    }
    __builtin_amdgcn_s_setprio(0);
    short8 pb0[2], pb1[2];
    softmax_pack(s0, m0r, l0r, o0, pb0, lgodd, cc);
    softmax_pack(s1, m1r, l1r, o1, pb1, lgodd, cc);
    __builtin_amdgcn_s_setprio(1);
#pragma unroll
    for (int c = 0; c < 4; ++c) {
      const unsigned short* vb = Vs + c * 1024 + lr * 64;
      short8 av0 = *reinterpret_cast<const short8*>(vb + so0);
      short8 av1 = *reinterpret_cast<const short8*>(vb + so1);
      o0[c] = __builtin_amdgcn_mfma_f32_16x16x32_bf16(av0, pb0[0], o0[c], 0, 0, 0);
      o1[c] = __builtin_amdgcn_mfma_f32_16x16x32_bf16(av0, pb1[0], o1[c], 0, 0, 0);
      o0[c] = __builtin_amdgcn_mfma_f32_16x16x32_bf16(av1, pb0[1], o0[c], 0, 0, 0);
      o1[c] = __builtin_amdgcn_mfma_f32_16x16x32_bf16(av1, pb1[1], o1[c], 0, 0, 0);
    }
    __builtin_amdgcn_s_setprio(0);
    __syncthreads();
  }

  const int b = bh >> 4, h = bh & 15;
#pragma unroll
  for (int g = 0; g < 2; ++g) {
    const float inv = 1.0f / (g ? l1r : l0r);
    const f32x4* o = g ? o1 : o0;
    const size_t row = (size_t)b * 2048 + q0 + g * 16 + lr;
#pragma unroll
    for (int c = 0; c < 4; ++c) {
      ushort4 pv;
      pv.x = f32_bf16(o[c][0] * inv);
      pv.y = f32_bf16(o[c][1] * inv);
      pv.z = f32_bf16(o[c][2] * inv);
      pv.w = f32_bf16(o[c][3] * inv);
      *reinterpret_cast<ushort4*>(const_cast<unsigned short*>(
          O + row * 1024 + h * 64 + c * 16 + lg * 4)) = pv;
    }
  }
#undef STAGE_KV
}

// ---------------- GEMM2: Ob(8192x1024) @ Woutt(1024x1024)^T + b -> out f32 ----------------
__global__ __launch_bounds__(256) void k_gemm_out(
    const unsigned short* __restrict__ Ob, const unsigned short* __restrict__ Wt,
    const float* __restrict__ bias, float* __restrict__ out) {
  __shared__ unsigned short lds[16384];
  f32x4 acc[4][4];
#pragma unroll
  for (int m = 0; m < 4; ++m)
#pragma unroll
    for (int n = 0; n < 4; ++n) acc[m][n] = (f32x4){0.f, 0.f, 0.f, 0.f};
  const int m0 = blockIdx.x * 128, n0 = blockIdx.y * 128;
  gemm_bt_mainloop(Ob, Wt, 1024, m0, n0, lds, threadIdx.x, acc);
  const int tid = threadIdx.x, w = tid >> 6, l = tid & 63;
  const int wr = w >> 1, wc = w & 1, lr = l & 15, lg = l >> 4;
#pragma unroll
  for (int n = 0; n < 4; ++n) {
    int gc = n0 + wc * 64 + n * 16 + lr;
    float bo = bias[gc];
#pragma unroll
    for (int m = 0; m < 4; ++m) {
      int gr = m0 + wr * 64 + m * 16 + lg * 4;
#pragma unroll
      for (int r = 0; r < 4; ++r)
        out[(size_t)(gr + r) * 1024 + gc] = acc[m][n][r] + bo;
    }
  }
}

extern "C" void kernel_launch(void* const* d_in, const int* in_sizes, int n_in,
                              void* d_out, int out_size, void* d_ws, size_t ws_size,
                              hipStream_t stream) {
  const float* z     = (const float*)d_in[0];
  const float* w_qkv = (const float*)d_in[1];
  const float* w_out = (const float*)d_in[2];
  const float* b_out = (const float*)d_in[3];
  float* out = (float*)d_out;

  unsigned short* ws = (unsigned short*)d_ws;
  unsigned short* Zb    = ws;              // 8192*1024      (reused as Ob after GEMM1)
  unsigned short* Wqkvt = ws + 8388608;    // 3072*1024
  unsigned short* Woutt = ws + 11534336;   // 1024*1024
  unsigned short* Qb    = ws + 12582912;   // B*H*N*DH
  unsigned short* Kb    = ws + 20971520;
  unsigned short* Vt    = ws + 29360128;
  unsigned short* Ob    = Zb;              // alias: Zb dead after GEMM1 (stream-ordered)

  k_cvt<<<dim3(8192), dim3(256), 0, stream>>>(z, Zb, 2097152);
  k_cvt_t<<<dim3(96, 32), dim3(256), 0, stream>>>(w_qkv, Wqkvt, 1024, 3072);
  k_cvt_t<<<dim3(32, 32), dim3(256), 0, stream>>>(w_out, Woutt, 1024, 1024);
  k_gemm_qkv<<<dim3(64, 24), dim3(256), 0, stream>>>(Zb, Wqkvt, Qb, Kb, Vt);
  k_attn<<<dim3(1024), dim3(256), 0, stream>>>(Qb, Kb, Vt, Ob);
  k_gemm_out<<<dim3(64, 8), dim3(256), 0, stream>>>(Ob, Woutt, b_out, out);
}

// Round 16
// 196.265 us; speedup vs baseline: 2.1485x; 1.0353x over previous
//
#include <hip/hip_runtime.h>
#include <hip/hip_bf16.h>
#include <cstdint>
#include <cstddef>

typedef __attribute__((ext_vector_type(8))) short short8;
typedef __attribute__((ext_vector_type(4))) float f32x4;
typedef __attribute__((ext_vector_type(4))) unsigned uint4v;

#define LDS_AS __attribute__((address_space(3)))
#define GLB_AS __attribute__((address_space(1)))

__device__ __forceinline__ unsigned short f32_bf16(float f) {
  unsigned u = __builtin_bit_cast(unsigned, f);
  u += 0x7fffu + ((u >> 16) & 1u);
  return (unsigned short)(u >> 16);
}

__device__ __forceinline__ unsigned cvt_pk_bf16(float lo, float hi) {
  unsigned r;
  asm("v_cvt_pk_bf16_f32 %0, %1, %2" : "=v"(r) : "v"(lo), "v"(hi));
  return r;
}

// ---------------- convert f32 -> bf16, 4 elems/thread ----------------
__global__ __launch_bounds__(256) void k_cvt(const float* __restrict__ in,
                                             unsigned short* __restrict__ out, int n4) {
  int i = blockIdx.x * 256 + threadIdx.x;
  if (i >= n4) return;
  float4 v = reinterpret_cast<const float4*>(in)[i];
  ushort4 o;
  o.x = f32_bf16(v.x); o.y = f32_bf16(v.y); o.z = f32_bf16(v.z); o.w = f32_bf16(v.w);
  reinterpret_cast<ushort4*>(out)[i] = o;
}

// ---- fused convert+transpose for BOTH weights (saves one launch) ----
// w_qkv (1024x3072) -> Wqkvt (3072x1024): blockIdx.x in [0,96)
// w_out (1024x1024) -> Woutt (1024x1024): blockIdx.x in [96,128)
__global__ __launch_bounds__(256) void k_cvt_t2(const float* __restrict__ wq,
                                                unsigned short* __restrict__ oq,
                                                const float* __restrict__ wo,
                                                unsigned short* __restrict__ oo) {
  __shared__ float t[32][33];
  int bx = blockIdx.x;
  const float* in;
  unsigned short* out;
  int C;
  if (bx < 96) { in = wq; out = oq; C = 3072; }
  else         { in = wo; out = oo; C = 1024; bx -= 96; }
  const int R = 1024;
  int c0 = bx * 32, r0 = blockIdx.y * 32;
  int lr = threadIdx.x & 31, lw = threadIdx.x >> 5;
#pragma unroll
  for (int i = 0; i < 32; i += 8)
    t[lw + i][lr] = in[(size_t)(r0 + lw + i) * C + c0 + lr];
  __syncthreads();
#pragma unroll
  for (int i = 0; i < 32; i += 8)
    out[(size_t)(c0 + lw + i) * R + r0 + lr] = f32_bf16(t[lr][lw + i]);
}

// ------ shared GEMM-BT mainloop (C = A * Bt^T), BK=64, XOR-swizzled LDS ------
// (round-14-verified)
__device__ __forceinline__ void gemm_bt_mainloop(
    const unsigned short* __restrict__ A, const unsigned short* __restrict__ Bt,
    int K, int m0, int n0, unsigned short* lds, int tid, f32x4 acc[4][4]) {
  const int w = tid >> 6, l = tid & 63;
  const int wr = w >> 1, wc = w & 1;
  const int lr = l & 15, lg = l >> 4;
  unsigned short* As = lds;         // [128][64] swizzled
  unsigned short* Bs = lds + 8192;  // [128][64] swizzled
  const int sslot = tid & 7;
  for (int kt = 0; kt < K; kt += 64) {
    __syncthreads();
#pragma unroll
    for (int i = 0; i < 4; ++i) {
      int idx = i * 256 + tid;
      int row = idx >> 3;
      int sw = sslot ^ (row & 7);
      __builtin_amdgcn_global_load_lds(
          (const GLB_AS unsigned int*)(A + (size_t)(m0 + row) * K + kt + sw * 8),
          (LDS_AS unsigned int*)(As + (size_t)idx * 8), 16, 0, 0);
    }
#pragma unroll
    for (int i = 0; i < 4; ++i) {
      int idx = i * 256 + tid;
      int row = idx >> 3;
      int sw = sslot ^ (row & 7);
      __builtin_amdgcn_global_load_lds(
          (const GLB_AS unsigned int*)(Bt + (size_t)(n0 + row) * K + kt + sw * 8),
          (LDS_AS unsigned int*)(Bs + (size_t)idx * 8), 16, 0, 0);
    }
    __syncthreads();
#pragma unroll
    for (int kc = 0; kc < 2; ++kc) {
      const int so = ((kc * 4 + lg) ^ (lr & 7)) * 8;  // frag row&7 == lr&7
      short8 a[4], b[4];
#pragma unroll
      for (int m = 0; m < 4; ++m)
        a[m] = *reinterpret_cast<const short8*>(As + (wr * 64 + m * 16 + lr) * 64 + so);
#pragma unroll
      for (int n = 0; n < 4; ++n)
        b[n] = *reinterpret_cast<const short8*>(Bs + (wc * 64 + n * 16 + lr) * 64 + so);
      __builtin_amdgcn_s_setprio(1);
#pragma unroll
      for (int m = 0; m < 4; ++m)
#pragma unroll
        for (int n = 0; n < 4; ++n)
          acc[m][n] = __builtin_amdgcn_mfma_f32_16x16x32_bf16(a[m], b[n], acc[m][n], 0, 0, 0);
      __builtin_amdgcn_s_setprio(0);
    }
  }
}

// ---------------- GEMM1: Zb(8192x1024) @ Wqkvt(3072x1024)^T -> Q,K,Vt ----------------
__global__ __launch_bounds__(256) void k_gemm_qkv(
    const unsigned short* __restrict__ Zb, const unsigned short* __restrict__ Wt,
    unsigned short* __restrict__ Qb, unsigned short* __restrict__ Kb,
    unsigned short* __restrict__ Vt) {
  __shared__ unsigned short lds[16384];
  f32x4 acc[4][4];
#pragma unroll
  for (int m = 0; m < 4; ++m)
#pragma unroll
    for (int n = 0; n < 4; ++n) acc[m][n] = (f32x4){0.f, 0.f, 0.f, 0.f};
  const int m0 = blockIdx.x * 128, n0 = blockIdx.y * 128;
  gemm_bt_mainloop(Zb, Wt, 1024, m0, n0, lds, threadIdx.x, acc);
  const int tid = threadIdx.x, w = tid >> 6, l = tid & 63;
  const int wr = w >> 1, wc = w & 1, lr = l & 15, lg = l >> 4;
#pragma unroll
  for (int n = 0; n < 4; ++n) {
    int gc = n0 + wc * 64 + n * 16;
    int part = gc >> 10;
    int within = gc & 1023;
    int h = within >> 6;
    int dhb = (within & 63) + lr;
#pragma unroll
    for (int m = 0; m < 4; ++m) {
      int gr = m0 + wr * 64 + m * 16 + lg * 4;
      int b = gr >> 11, pos = gr & 2047;
      size_t bh = (size_t)(b * 16 + h);
      if (part == 0) {
        unsigned short* dst = Qb + bh * (2048 * 64) + (size_t)pos * 64 + dhb;
#pragma unroll
        for (int r = 0; r < 4; ++r) dst[r * 64] = f32_bf16(acc[m][n][r]);
      } else if (part == 1) {
        unsigned short* dst = Kb + bh * (2048 * 64) + (size_t)pos * 64 + dhb;
#pragma unroll
        for (int r = 0; r < 4; ++r) dst[r * 64] = f32_bf16(acc[m][n][r]);
      } else {
        unsigned short* dst = Vt + bh * (64 * 2048) + (size_t)dhb * 2048 + pos;
        ushort4 pv;
        pv.x = f32_bf16(acc[m][n][0]); pv.y = f32_bf16(acc[m][n][1]);
        pv.z = f32_bf16(acc[m][n][2]); pv.w = f32_bf16(acc[m][n][3]);
        *reinterpret_cast<ushort4*>(dst) = pv;
      }
    }
  }
}

// -------- softmax + P-pack for one 16-q group (defer-max THR=8, shuffle l-sum) ----
// Round-10-verified version.
__device__ __forceinline__ void softmax_pack(f32x4 s[4], float& m_r, float& l_r,
                                             f32x4 o[4], short8 pb[2], bool lgodd,
                                             float cc) {
  float t0 = fmaxf(fmaxf(s[0][0], s[0][1]), s[0][2]);
  float t1 = fmaxf(fmaxf(s[0][3], s[1][0]), s[1][1]);
  float t2 = fmaxf(fmaxf(s[1][2], s[1][3]), s[2][0]);
  float t3 = fmaxf(fmaxf(s[2][1], s[2][2]), s[2][3]);
  float t4 = fmaxf(fmaxf(s[3][0], s[3][1]), s[3][2]);
  float tl = fmaxf(fmaxf(fmaxf(t0, t1), fmaxf(t2, t3)), fmaxf(t4, s[3][3]));
  if (__any(tl > m_r + 8.0f)) {  // rare after early tiles
    float tm = fmaxf(tl, __shfl_xor(tl, 16));
    tm = fmaxf(tm, __shfl_xor(tm, 32));
    float mn = fmaxf(m_r, tm);
    float al = __builtin_amdgcn_exp2f((m_r - mn) * cc);
    m_r = mn;
    l_r *= al;
#pragma unroll
    for (int c = 0; c < 4; ++c)
#pragma unroll
      for (int r = 0; r < 4; ++r) o[c][r] *= al;
  }
  float nb = m_r * cc;
  float rs = 0.f;
#pragma unroll
  for (int c = 0; c < 4; ++c)
#pragma unroll
    for (int r = 0; r < 4; ++r) {
      float p = __builtin_amdgcn_exp2f(s[c][r] * cc - nb);
      s[c][r] = p;
      rs += p;
    }
  rs += __shfl_xor(rs, 16);
  rs += __shfl_xor(rs, 32);
  l_r += rs;
  unsigned Ap[4], Bp[4];
#pragma unroll
  for (int c = 0; c < 4; ++c) {
    Ap[c] = cvt_pk_bf16(s[c][0], s[c][1]);
    Bp[c] = cvt_pk_bf16(s[c][2], s[c][3]);
  }
#pragma unroll
  for (int kc = 0; kc < 2; ++kc) {
    unsigned ua = Ap[2 * kc], va = Ap[2 * kc + 1];
    asm("v_permlane32_swap_b32 %0, %1" : "+v"(ua), "+v"(va));
    unsigned uas = (unsigned)__shfl_xor((int)ua, 16);
    unsigned vas = (unsigned)__shfl_xor((int)va, 16);
    unsigned w0 = lgodd ? vas : ua;
    unsigned w2 = lgodd ? va : uas;
    unsigned ub = Bp[2 * kc], vb = Bp[2 * kc + 1];
    asm("v_permlane32_swap_b32 %0, %1" : "+v"(ub), "+v"(vb));
    unsigned ubs = (unsigned)__shfl_xor((int)ub, 16);
    unsigned vbs = (unsigned)__shfl_xor((int)vb, 16);
    unsigned w1 = lgodd ? vbs : ub;
    unsigned w3 = lgodd ? vb : ubs;
    uint4v pw = (uint4v){w0, w1, w2, w3};
    pb[kc] = __builtin_bit_cast(short8, pw);
  }
}

// ------- flash attention v8: 512 threads, 256 q/block (staging amortized 2x) ------
// Same per-wave math/layout as round-10-verified kernel; 2 blocks/CU x 8 waves.
__global__ __launch_bounds__(512, 4) void k_attn(
    const unsigned short* __restrict__ Q, const unsigned short* __restrict__ Kb,
    const unsigned short* __restrict__ Vt, unsigned short* __restrict__ O) {
  __shared__ unsigned short lds[16384];  // [2][K 4096 | V 4096] shorts
  const int tid = threadIdx.x, w = tid >> 6, l = tid & 63;
  const int lr = l & 15, lg = l >> 4;
  const bool lgodd = (lg & 1) != 0;
  // XCD-aware remap: 8 q-blocks of one (b,h) share wg&7 -> same XCD.
  // Bijective: wg bits [2:0]=xcd, [5:3]=qb, [8:6]=ghi; bh = xcd + 8*ghi.
  const int wg = blockIdx.x;
  const int xcd = wg & 7, local = wg >> 3;
  const int bh = xcd + ((local >> 3) << 3);
  const int qb = local & 7;
  const unsigned short* Qp = Q + (size_t)bh * (2048 * 64);
  const unsigned short* Kp = Kb + (size_t)bh * (2048 * 64);
  const unsigned short* Vp = Vt + (size_t)bh * (64 * 2048);
  const int q0 = qb * 256 + w * 32;

  short8 aq[2][2];
#pragma unroll
  for (int g = 0; g < 2; ++g)
#pragma unroll
    for (int kc = 0; kc < 2; ++kc)
      aq[g][kc] = *reinterpret_cast<const short8*>(
          Qp + (size_t)(q0 + g * 16 + lr) * 64 + kc * 32 + lg * 8);

  float m0r = -3e38f, l0r = 0.f, m1r = -3e38f, l1r = 0.f;
  f32x4 o0[4], o1[4];
#pragma unroll
  for (int c = 0; c < 4; ++c) {
    o0[c] = (f32x4){0.f, 0.f, 0.f, 0.f};
    o1[c] = (f32x4){0.f, 0.f, 0.f, 0.f};
  }
  const f32x4 zero4 = (f32x4){0.f, 0.f, 0.f, 0.f};
  const float cc = 0.125f * 1.44269504089f;  // SCALE * log2(e)

  // loop-invariant swizzle offsets: frag row&7 == lr&7 (c*16 = 0 mod 8)
  const int so0 = (lg ^ (lr & 7)) * 8;
  const int so1 = ((4 + lg) ^ (lr & 7)) * 8;

  // staging: 512 threads cover all 64 rows of K and V in ONE pass (2 loads/thread)
  const int srow = tid >> 3, sslot = tid & 7;
  const int ssw = sslot ^ (srow & 7);
#define STAGE_KV(bufK, bufV, kv0)                                                     \
  {                                                                                   \
    __builtin_amdgcn_global_load_lds(                                                 \
        (const GLB_AS unsigned int*)(Kp + (size_t)((kv0) + srow) * 64 + ssw * 8),     \
        (LDS_AS unsigned int*)((bufK) + tid * 8), 16, 0, 0);                          \
    __builtin_amdgcn_global_load_lds(                                                 \
        (const GLB_AS unsigned int*)(Vp + (size_t)srow * 2048 + (kv0) + ssw * 8),     \
        (LDS_AS unsigned int*)((bufV) + tid * 8), 16, 0, 0);                          \
  }

  unsigned short* K0 = lds;
  unsigned short* V0 = lds + 4096;
  unsigned short* K1 = lds + 8192;
  unsigned short* V1 = lds + 12288;

  STAGE_KV(K0, V0, 0);
  __syncthreads();

  for (int t = 0; t < 32; ++t) {
    unsigned short* Ks = (t & 1) ? K1 : K0;
    unsigned short* Vs = (t & 1) ? V1 : V0;
    if (t < 31) {
      unsigned short* Kn = (t & 1) ? K0 : K1;
      unsigned short* Vn = (t & 1) ? V0 : V1;
      STAGE_KV(Kn, Vn, (t + 1) * 64);
    }
    f32x4 s0[4], s1[4];
    __builtin_amdgcn_s_setprio(1);
#pragma unroll
    for (int c = 0; c < 4; ++c) {
      const unsigned short* kb = Ks + c * 1024 + lr * 64;
      short8 ak0 = *reinterpret_cast<const short8*>(kb + so0);
      short8 ak1 = *reinterpret_cast<const short8*>(kb + so1);
      s0[c] = __builtin_amdgcn_mfma_f32_16x16x32_bf16(ak0, aq[0][0], zero4, 0, 0, 0);
      s1[c] = __builtin_amdgcn_mfma_f32_16x16x32_bf16(ak0, aq[1][0], zero4, 0, 0, 0);
      s0[c] = __builtin_amdgcn_mfma_f32_16x16x32_bf16(ak1, aq[0][1], s0[c], 0, 0, 0);
      s1[c] = __builtin_amdgcn_mfma_f32_16x16x32_bf16(ak1, aq[1][1], s1[c], 0, 0, 0);
    }
    __builtin_amdgcn_s_setprio(0);
    short8 pb0[2], pb1[2];
    softmax_pack(s0, m0r, l0r, o0, pb0, lgodd, cc);
    softmax_pack(s1, m1r, l1r, o1, pb1, lgodd, cc);
    __builtin_amdgcn_s_setprio(1);
#pragma unroll
    for (int c = 0; c < 4; ++c) {
      const unsigned short* vb = Vs + c * 1024 + lr * 64;
      short8 av0 = *reinterpret_cast<const short8*>(vb + so0);
      short8 av1 = *reinterpret_cast<const short8*>(vb + so1);
      o0[c] = __builtin_amdgcn_mfma_f32_16x16x32_bf16(av0, pb0[0], o0[c], 0, 0, 0);
      o1[c] = __builtin_amdgcn_mfma_f32_16x16x32_bf16(av0, pb1[0], o1[c], 0, 0, 0);
      o0[c] = __builtin_amdgcn_mfma_f32_16x16x32_bf16(av1, pb0[1], o0[c], 0, 0, 0);
      o1[c] = __builtin_amdgcn_mfma_f32_16x16x32_bf16(av1, pb1[1], o1[c], 0, 0, 0);
    }
    __builtin_amdgcn_s_setprio(0);
    __syncthreads();
  }

  const int b = bh >> 4, h = bh & 15;
#pragma unroll
  for (int g = 0; g < 2; ++g) {
    const float inv = 1.0f / (g ? l1r : l0r);
    const f32x4* o = g ? o1 : o0;
    const size_t row = (size_t)b * 2048 + q0 + g * 16 + lr;
#pragma unroll
    for (int c = 0; c < 4; ++c) {
      ushort4 pv;
      pv.x = f32_bf16(o[c][0] * inv);
      pv.y = f32_bf16(o[c][1] * inv);
      pv.z = f32_bf16(o[c][2] * inv);
      pv.w = f32_bf16(o[c][3] * inv);
      *reinterpret_cast<ushort4*>(const_cast<unsigned short*>(
          O + row * 1024 + h * 64 + c * 16 + lg * 4)) = pv;
    }
  }
#undef STAGE_KV
}

// ---------------- GEMM2: Ob(8192x1024) @ Woutt(1024x1024)^T + b -> out f32 ----------------
__global__ __launch_bounds__(256) void k_gemm_out(
    const unsigned short* __restrict__ Ob, const unsigned short* __restrict__ Wt,
    const float* __restrict__ bias, float* __restrict__ out) {
  __shared__ unsigned short lds[16384];
  f32x4 acc[4][4];
#pragma unroll
  for (int m = 0; m < 4; ++m)
#pragma unroll
    for (int n = 0; n < 4; ++n) acc[m][n] = (f32x4){0.f, 0.f, 0.f, 0.f};
  const int m0 = blockIdx.x * 128, n0 = blockIdx.y * 128;
  gemm_bt_mainloop(Ob, Wt, 1024, m0, n0, lds, threadIdx.x, acc);
  const int tid = threadIdx.x, w = tid >> 6, l = tid & 63;
  const int wr = w >> 1, wc = w & 1, lr = l & 15, lg = l >> 4;
#pragma unroll
  for (int n = 0; n < 4; ++n) {
    int gc = n0 + wc * 64 + n * 16 + lr;
    float bo = bias[gc];
#pragma unroll
    for (int m = 0; m < 4; ++m) {
      int gr = m0 + wr * 64 + m * 16 + lg * 4;
#pragma unroll
      for (int r = 0; r < 4; ++r)
        out[(size_t)(gr + r) * 1024 + gc] = acc[m][n][r] + bo;
    }
  }
}

extern "C" void kernel_launch(void* const* d_in, const int* in_sizes, int n_in,
                              void* d_out, int out_size, void* d_ws, size_t ws_size,
                              hipStream_t stream) {
  const float* z     = (const float*)d_in[0];
  const float* w_qkv = (const float*)d_in[1];
  const float* w_out = (const float*)d_in[2];
  const float* b_out = (const float*)d_in[3];
  float* out = (float*)d_out;

  unsigned short* ws = (unsigned short*)d_ws;
  unsigned short* Zb    = ws;              // 8192*1024      (reused as Ob after GEMM1)
  unsigned short* Wqkvt = ws + 8388608;    // 3072*1024
  unsigned short* Woutt = ws + 11534336;   // 1024*1024
  unsigned short* Qb    = ws + 12582912;   // B*H*N*DH
  unsigned short* Kb    = ws + 20971520;
  unsigned short* Vt    = ws + 29360128;
  unsigned short* Ob    = Zb;              // alias: Zb dead after GEMM1 (stream-ordered)

  k_cvt<<<dim3(8192), dim3(256), 0, stream>>>(z, Zb, 2097152);
  k_cvt_t2<<<dim3(128, 32), dim3(256), 0, stream>>>(w_qkv, Wqkvt, w_out, Woutt);
  k_gemm_qkv<<<dim3(64, 24), dim3(256), 0, stream>>>(Zb, Wqkvt, Qb, Kb, Vt);
  k_attn<<<dim3(512), dim3(512), 0, stream>>>(Qb, Kb, Vt, Ob);
  k_gemm_out<<<dim3(64, 8), dim3(256), 0, stream>>>(Ob, Woutt, b_out, out);
}

// Round 18
// 195.182 us; speedup vs baseline: 2.1605x; 1.0055x over previous
//
#include <hip/hip_runtime.h>
#include <hip/hip_bf16.h>
#include <cstdint>
#include <cstddef>

typedef __attribute__((ext_vector_type(8))) short short8;
typedef __attribute__((ext_vector_type(4))) float f32x4;
typedef __attribute__((ext_vector_type(4))) unsigned uint4v;

#define LDS_AS __attribute__((address_space(3)))
#define GLB_AS __attribute__((address_space(1)))

__device__ __forceinline__ unsigned short f32_bf16(float f) {
  unsigned u = __builtin_bit_cast(unsigned, f);
  u += 0x7fffu + ((u >> 16) & 1u);
  return (unsigned short)(u >> 16);
}

__device__ __forceinline__ unsigned cvt_pk_bf16(float lo, float hi) {
  unsigned r;
  asm("v_cvt_pk_bf16_f32 %0, %1, %2" : "=v"(r) : "v"(lo), "v"(hi));
  return r;
}

// ---------------- convert f32 -> bf16, 4 elems/thread ----------------
__global__ __launch_bounds__(256) void k_cvt(const float* __restrict__ in,
                                             unsigned short* __restrict__ out, int n4) {
  int i = blockIdx.x * 256 + threadIdx.x;
  if (i >= n4) return;
  float4 v = reinterpret_cast<const float4*>(in)[i];
  ushort4 o;
  o.x = f32_bf16(v.x); o.y = f32_bf16(v.y); o.z = f32_bf16(v.z); o.w = f32_bf16(v.w);
  reinterpret_cast<ushort4*>(out)[i] = o;
}

// ---- fused convert+transpose for BOTH weights (round-16-verified) ----
__global__ __launch_bounds__(256) void k_cvt_t2(const float* __restrict__ wq,
                                                unsigned short* __restrict__ oq,
                                                const float* __restrict__ wo,
                                                unsigned short* __restrict__ oo) {
  __shared__ float t[32][33];
  int bx = blockIdx.x;
  const float* in;
  unsigned short* out;
  int C;
  if (bx < 96) { in = wq; out = oq; C = 3072; }
  else         { in = wo; out = oo; C = 1024; bx -= 96; }
  const int R = 1024;
  int c0 = bx * 32, r0 = blockIdx.y * 32;
  int lr = threadIdx.x & 31, lw = threadIdx.x >> 5;
#pragma unroll
  for (int i = 0; i < 32; i += 8)
    t[lw + i][lr] = in[(size_t)(r0 + lw + i) * C + c0 + lr];
  __syncthreads();
#pragma unroll
  for (int i = 0; i < 32; i += 8)
    out[(size_t)(c0 + lw + i) * R + r0 + lr] = f32_bf16(t[lr][lw + i]);
}

// ------ shared GEMM-BT mainloop (C = A * Bt^T), BK=64, XOR-swizzled LDS ------
// (round-14-verified)
__device__ __forceinline__ void gemm_bt_mainloop(
    const unsigned short* __restrict__ A, const unsigned short* __restrict__ Bt,
    int K, int m0, int n0, unsigned short* lds, int tid, f32x4 acc[4][4]) {
  const int w = tid >> 6, l = tid & 63;
  const int wr = w >> 1, wc = w & 1;
  const int lr = l & 15, lg = l >> 4;
  unsigned short* As = lds;         // [128][64] swizzled
  unsigned short* Bs = lds + 8192;  // [128][64] swizzled
  const int sslot = tid & 7;
  for (int kt = 0; kt < K; kt += 64) {
    __syncthreads();
#pragma unroll
    for (int i = 0; i < 4; ++i) {
      int idx = i * 256 + tid;
      int row = idx >> 3;
      int sw = sslot ^ (row & 7);
      __builtin_amdgcn_global_load_lds(
          (const GLB_AS unsigned int*)(A + (size_t)(m0 + row) * K + kt + sw * 8),
          (LDS_AS unsigned int*)(As + (size_t)idx * 8), 16, 0, 0);
    }
#pragma unroll
    for (int i = 0; i < 4; ++i) {
      int idx = i * 256 + tid;
      int row = idx >> 3;
      int sw = sslot ^ (row & 7);
      __builtin_amdgcn_global_load_lds(
          (const GLB_AS unsigned int*)(Bt + (size_t)(n0 + row) * K + kt + sw * 8),
          (LDS_AS unsigned int*)(Bs + (size_t)idx * 8), 16, 0, 0);
    }
    __syncthreads();
#pragma unroll
    for (int kc = 0; kc < 2; ++kc) {
      const int so = ((kc * 4 + lg) ^ (lr & 7)) * 8;  // frag row&7 == lr&7
      short8 a[4], b[4];
#pragma unroll
      for (int m = 0; m < 4; ++m)
        a[m] = *reinterpret_cast<const short8*>(As + (wr * 64 + m * 16 + lr) * 64 + so);
#pragma unroll
      for (int n = 0; n < 4; ++n)
        b[n] = *reinterpret_cast<const short8*>(Bs + (wc * 64 + n * 16 + lr) * 64 + so);
      __builtin_amdgcn_s_setprio(1);
#pragma unroll
      for (int m = 0; m < 4; ++m)
#pragma unroll
        for (int n = 0; n < 4; ++n)
          acc[m][n] = __builtin_amdgcn_mfma_f32_16x16x32_bf16(a[m], b[n], acc[m][n], 0, 0, 0);
      __builtin_amdgcn_s_setprio(0);
    }
  }
}

// ---------------- GEMM1: Zb(8192x1024) @ Wqkvt(3072x1024)^T -> Q,K,Vt ----------------
__global__ __launch_bounds__(256) void k_gemm_qkv(
    const unsigned short* __restrict__ Zb, const unsigned short* __restrict__ Wt,
    unsigned short* __restrict__ Qb, unsigned short* __restrict__ Kb,
    unsigned short* __restrict__ Vt) {
  __shared__ unsigned short lds[16384];
  f32x4 acc[4][4];
#pragma unroll
  for (int m = 0; m < 4; ++m)
#pragma unroll
    for (int n = 0; n < 4; ++n) acc[m][n] = (f32x4){0.f, 0.f, 0.f, 0.f};
  const int m0 = blockIdx.x * 128, n0 = blockIdx.y * 128;
  gemm_bt_mainloop(Zb, Wt, 1024, m0, n0, lds, threadIdx.x, acc);
  const int tid = threadIdx.x, w = tid >> 6, l = tid & 63;
  const int wr = w >> 1, wc = w & 1, lr = l & 15, lg = l >> 4;
#pragma unroll
  for (int n = 0; n < 4; ++n) {
    int gc = n0 + wc * 64 + n * 16;
    int part = gc >> 10;
    int within = gc & 1023;
    int h = within >> 6;
    int dhb = (within & 63) + lr;
#pragma unroll
    for (int m = 0; m < 4; ++m) {
      int gr = m0 + wr * 64 + m * 16 + lg * 4;
      int b = gr >> 11, pos = gr & 2047;
      size_t bh = (size_t)(b * 16 + h);
      if (part == 0) {
        unsigned short* dst = Qb + bh * (2048 * 64) + (size_t)pos * 64 + dhb;
#pragma unroll
        for (int r = 0; r < 4; ++r) dst[r * 64] = f32_bf16(acc[m][n][r]);
      } else if (part == 1) {
        unsigned short* dst = Kb + bh * (2048 * 64) + (size_t)pos * 64 + dhb;
#pragma unroll
        for (int r = 0; r < 4; ++r) dst[r * 64] = f32_bf16(acc[m][n][r]);
      } else {
        unsigned short* dst = Vt + bh * (64 * 2048) + (size_t)dhb * 2048 + pos;
        ushort4 pv;
        pv.x = f32_bf16(acc[m][n][0]); pv.y = f32_bf16(acc[m][n][1]);
        pv.z = f32_bf16(acc[m][n][2]); pv.w = f32_bf16(acc[m][n][3]);
        *reinterpret_cast<ushort4*>(dst) = pv;
      }
    }
  }
}

// -------- softmax + P-pack for one 16-q group (defer-max THR=8, shuffle l-sum) ----
// Round-10-verified version.
__device__ __forceinline__ void softmax_pack(f32x4 s[4], float& m_r, float& l_r,
                                             f32x4 o[4], short8 pb[2], bool lgodd,
                                             float cc) {
  float t0 = fmaxf(fmaxf(s[0][0], s[0][1]), s[0][2]);
  float t1 = fmaxf(fmaxf(s[0][3], s[1][0]), s[1][1]);
  float t2 = fmaxf(fmaxf(s[1][2], s[1][3]), s[2][0]);
  float t3 = fmaxf(fmaxf(s[2][1], s[2][2]), s[2][3]);
  float t4 = fmaxf(fmaxf(s[3][0], s[3][1]), s[3][2]);
  float tl = fmaxf(fmaxf(fmaxf(t0, t1), fmaxf(t2, t3)), fmaxf(t4, s[3][3]));
  if (__any(tl > m_r + 8.0f)) {  // rare after early tiles
    float tm = fmaxf(tl, __shfl_xor(tl, 16));
    tm = fmaxf(tm, __shfl_xor(tm, 32));
    float mn = fmaxf(m_r, tm);
    float al = __builtin_amdgcn_exp2f((m_r - mn) * cc);
    m_r = mn;
    l_r *= al;
#pragma unroll
    for (int c = 0; c < 4; ++c)
#pragma unroll
      for (int r = 0; r < 4; ++r) o[c][r] *= al;
  }
  float nb = m_r * cc;
  float rs = 0.f;
#pragma unroll
  for (int c = 0; c < 4; ++c)
#pragma unroll
    for (int r = 0; r < 4; ++r) {
      float p = __builtin_amdgcn_exp2f(s[c][r] * cc - nb);
      s[c][r] = p;
      rs += p;
    }
  rs += __shfl_xor(rs, 16);
  rs += __shfl_xor(rs, 32);
  l_r += rs;
  unsigned Ap[4], Bp[4];
#pragma unroll
  for (int c = 0; c < 4; ++c) {
    Ap[c] = cvt_pk_bf16(s[c][0], s[c][1]);
    Bp[c] = cvt_pk_bf16(s[c][2], s[c][3]);
  }
#pragma unroll
  for (int kc = 0; kc < 2; ++kc) {
    unsigned ua = Ap[2 * kc], va = Ap[2 * kc + 1];
    asm("v_permlane32_swap_b32 %0, %1" : "+v"(ua), "+v"(va));
    unsigned uas = (unsigned)__shfl_xor((int)ua, 16);
    unsigned vas = (unsigned)__shfl_xor((int)va, 16);
    unsigned w0 = lgodd ? vas : ua;
    unsigned w2 = lgodd ? va : uas;
    unsigned ub = Bp[2 * kc], vb = Bp[2 * kc + 1];
    asm("v_permlane32_swap_b32 %0, %1" : "+v"(ub), "+v"(vb));
    unsigned ubs = (unsigned)__shfl_xor((int)ub, 16);
    unsigned vbs = (unsigned)__shfl_xor((int)vb, 16);
    unsigned w1 = lgodd ? vbs : ub;
    unsigned w3 = lgodd ? vb : ubs;
    uint4v pw = (uint4v){w0, w1, w2, w3};
    pb[kc] = __builtin_bit_cast(short8, pw);
  }
}

// ------- flash attention v9: 512 threads, 256 q/block, KVBLK=128 epoch ------------
// Two 64-key sub-tiles per barrier epoch (barriers 32 -> 16). Sub-tile compute body
// and per-sub-tile LDS layout identical to round-16-verified v8.
__global__ __launch_bounds__(512, 4) void k_attn(
    const unsigned short* __restrict__ Q, const unsigned short* __restrict__ Kb,
    const unsigned short* __restrict__ Vt, unsigned short* __restrict__ O) {
  __shared__ unsigned short lds[32768];  // [2 buf][K 8192 | V 8192] shorts = 64 KB
  const int tid = threadIdx.x, w = tid >> 6, l = tid & 63;
  const int lr = l & 15, lg = l >> 4;
  const bool lgodd = (lg & 1) != 0;
  // XCD-aware remap (verified): 8 q-blocks of one (b,h) share wg&7 -> same XCD.
  const int wg = blockIdx.x;
  const int xcd = wg & 7, local = wg >> 3;
  const int bh = xcd + ((local >> 3) << 3);
  const int qb = local & 7;
  const unsigned short* Qp = Q + (size_t)bh * (2048 * 64);
  const unsigned short* Kp = Kb + (size_t)bh * (2048 * 64);
  const unsigned short* Vp = Vt + (size_t)bh * (64 * 2048);
  const int q0 = qb * 256 + w * 32;

  short8 aq[2][2];
#pragma unroll
  for (int g = 0; g < 2; ++g)
#pragma unroll
    for (int kc = 0; kc < 2; ++kc)
      aq[g][kc] = *reinterpret_cast<const short8*>(
          Qp + (size_t)(q0 + g * 16 + lr) * 64 + kc * 32 + lg * 8);

  float m0r = -3e38f, l0r = 0.f, m1r = -3e38f, l1r = 0.f;
  f32x4 o0[4], o1[4];
#pragma unroll
  for (int c = 0; c < 4; ++c) {
    o0[c] = (f32x4){0.f, 0.f, 0.f, 0.f};
    o1[c] = (f32x4){0.f, 0.f, 0.f, 0.f};
  }
  const f32x4 zero4 = (f32x4){0.f, 0.f, 0.f, 0.f};
  const float cc = 0.125f * 1.44269504089f;  // SCALE * log2(e)

  // loop-invariant swizzle offsets: frag row&7 == lr&7 (c*16 = 0 mod 8)
  const int so0 = (lg ^ (lr & 7)) * 8;
  const int so1 = ((4 + lg) ^ (lr & 7)) * 8;

  // staging: per epoch, K 128 rows (2 chunks/thread) + V 2 sub-tiles (2 chunks)
  const int srow = tid >> 3, sslot = tid & 7;
  const int ssw = sslot ^ (srow & 7);  // srow&7 == row&7 for both K halves (64%8==0)
#define STAGE_KV(bufK, bufV, kv0)                                                     \
  {                                                                                   \
    _Pragma("unroll")                                                                 \
    for (int s = 0; s < 2; ++s) {                                                     \
      __builtin_amdgcn_global_load_lds(                                               \
          (const GLB_AS unsigned int*)(Kp + (size_t)((kv0) + s * 64 + srow) * 64 +    \
                                       ssw * 8),                                      \
          (LDS_AS unsigned int*)((bufK) + (s * 512 + tid) * 8), 16, 0, 0);            \
      __builtin_amdgcn_global_load_lds(                                               \
          (const GLB_AS unsigned int*)(Vp + (size_t)srow * 2048 + (kv0) + s * 64 +    \
                                       ssw * 8),                                      \
          (LDS_AS unsigned int*)((bufV) + (s * 4096 + tid * 8)), 16, 0, 0);           \
    }                                                                                 \
  }

  unsigned short* K0 = lds;              // [128][64] (two 64-row sub-tiles)
  unsigned short* V0 = lds + 8192;       // two [64][64] sub-tiles
  unsigned short* K1 = lds + 16384;
  unsigned short* V1 = lds + 24576;

  STAGE_KV(K0, V0, 0);
  __syncthreads();

  for (int t = 0; t < 16; ++t) {
    unsigned short* Ks = (t & 1) ? K1 : K0;
    unsigned short* Vs = (t & 1) ? V1 : V0;
    if (t < 15) {
      unsigned short* Kn = (t & 1) ? K0 : K1;
      unsigned short* Vn = (t & 1) ? V0 : V1;
      STAGE_KV(Kn, Vn, (t + 1) * 128);
    }
#pragma unroll
    for (int sub = 0; sub < 2; ++sub) {
      const unsigned short* Kt = Ks + sub * 4096;
      const unsigned short* Vb = Vs + sub * 4096;
      f32x4 s0[4], s1[4];
      __builtin_amdgcn_s_setprio(1);
#pragma unroll
      for (int c = 0; c < 4; ++c) {
        const unsigned short* kb = Kt + c * 1024 + lr * 64;
        short8 ak0 = *reinterpret_cast<const short8*>(kb + so0);
        short8 ak1 = *reinterpret_cast<const short8*>(kb + so1);
        s0[c] = __builtin_amdgcn_mfma_f32_16x16x32_bf16(ak0, aq[0][0], zero4, 0, 0, 0);
        s1[c] = __builtin_amdgcn_mfma_f32_16x16x32_bf16(ak0, aq[1][0], zero4, 0, 0, 0);
        s0[c] = __builtin_amdgcn_mfma_f32_16x16x32_bf16(ak1, aq[0][1], s0[c], 0, 0, 0);
        s1[c] = __builtin_amdgcn_mfma_f32_16x16x32_bf16(ak1, aq[1][1], s1[c], 0, 0, 0);
      }
      __builtin_amdgcn_s_setprio(0);
      short8 pb0[2], pb1[2];
      softmax_pack(s0, m0r, l0r, o0, pb0, lgodd, cc);
      softmax_pack(s1, m1r, l1r, o1, pb1, lgodd, cc);
      __builtin_amdgcn_s_setprio(1);
#pragma unroll
      for (int c = 0; c < 4; ++c) {
        const unsigned short* vb = Vb + c * 1024 + lr * 64;
        short8 av0 = *reinterpret_cast<const short8*>(vb + so0);
        short8 av1 = *reinterpret_cast<const short8*>(vb + so1);
        o0[c] = __builtin_amdgcn_mfma_f32_16x16x32_bf16(av0, pb0[0], o0[c], 0, 0, 0);
        o1[c] = __builtin_amdgcn_mfma_f32_16x16x32_bf16(av0, pb1[0], o1[c], 0, 0, 0);
        o0[c] = __builtin_amdgcn_mfma_f32_16x16x32_bf16(av1, pb0[1], o0[c], 0, 0, 0);
        o1[c] = __builtin_amdgcn_mfma_f32_16x16x32_bf16(av1, pb1[1], o1[c], 0, 0, 0);
      }
      __builtin_amdgcn_s_setprio(0);
    }
    __syncthreads();
  }

  const int b = bh >> 4, h = bh & 15;
#pragma unroll
  for (int g = 0; g < 2; ++g) {
    const float inv = 1.0f / (g ? l1r : l0r);
    const f32x4* o = g ? o1 : o0;
    const size_t row = (size_t)b * 2048 + q0 + g * 16 + lr;
#pragma unroll
    for (int c = 0; c < 4; ++c) {
      ushort4 pv;
      pv.x = f32_bf16(o[c][0] * inv);
      pv.y = f32_bf16(o[c][1] * inv);
      pv.z = f32_bf16(o[c][2] * inv);
      pv.w = f32_bf16(o[c][3] * inv);
      *reinterpret_cast<ushort4*>(const_cast<unsigned short*>(
          O + row * 1024 + h * 64 + c * 16 + lg * 4)) = pv;
    }
  }
#undef STAGE_KV
}

// ---------------- GEMM2: Ob(8192x1024) @ Woutt(1024x1024)^T + b -> out f32 ----------------
__global__ __launch_bounds__(256) void k_gemm_out(
    const unsigned short* __restrict__ Ob, const unsigned short* __restrict__ Wt,
    const float* __restrict__ bias, float* __restrict__ out) {
  __shared__ unsigned short lds[16384];
  f32x4 acc[4][4];
#pragma unroll
  for (int m = 0; m < 4; ++m)
#pragma unroll
    for (int n = 0; n < 4; ++n) acc[m][n] = (f32x4){0.f, 0.f, 0.f, 0.f};
  const int m0 = blockIdx.x * 128, n0 = blockIdx.y * 128;
  gemm_bt_mainloop(Ob, Wt, 1024, m0, n0, lds, threadIdx.x, acc);
  const int tid = threadIdx.x, w = tid >> 6, l = tid & 63;
  const int wr = w >> 1, wc = w & 1, lr = l & 15, lg = l >> 4;
#pragma unroll
  for (int n = 0; n < 4; ++n) {
    int gc = n0 + wc * 64 + n * 16 + lr;
    float bo = bias[gc];
#pragma unroll
    for (int m = 0; m < 4; ++m) {
      int gr = m0 + wr * 64 + m * 16 + lg * 4;
#pragma unroll
      for (int r = 0; r < 4; ++r)
        out[(size_t)(gr + r) * 1024 + gc] = acc[m][n][r] + bo;
    }
  }
}

extern "C" void kernel_launch(void* const* d_in, const int* in_sizes, int n_in,
                              void* d_out, int out_size, void* d_ws, size_t ws_size,
                              hipStream_t stream) {
  const float* z     = (const float*)d_in[0];
  const float* w_qkv = (const float*)d_in[1];
  const float* w_out = (const float*)d_in[2];
  const float* b_out = (const float*)d_in[3];
  float* out = (float*)d_out;

  unsigned short* ws = (unsigned short*)d_ws;
  unsigned short* Zb    = ws;              // 8192*1024      (reused as Ob after GEMM1)
  unsigned short* Wqkvt = ws + 8388608;    // 3072*1024
  unsigned short* Woutt = ws + 11534336;   // 1024*1024
  unsigned short* Qb    = ws + 12582912;   // B*H*N*DH
  unsigned short* Kb    = ws + 20971520;
  unsigned short* Vt    = ws + 29360128;
  unsigned short* Ob    = Zb;              // alias: Zb dead after GEMM1 (stream-ordered)

  k_cvt<<<dim3(8192), dim3(256), 0, stream>>>(z, Zb, 2097152);
  k_cvt_t2<<<dim3(128, 32), dim3(256), 0, stream>>>(w_qkv, Wqkvt, w_out, Woutt);
  k_gemm_qkv<<<dim3(64, 24), dim3(256), 0, stream>>>(Zb, Wqkvt, Qb, Kb, Vt);
  k_attn<<<dim3(512), dim3(512), 0, stream>>>(Qb, Kb, Vt, Ob);
  k_gemm_out<<<dim3(64, 8), dim3(256), 0, stream>>>(Ob, Woutt, b_out, out);
}

// Round 19
// 194.398 us; speedup vs baseline: 2.1692x; 1.0040x over previous
//
#include <hip/hip_runtime.h>
#include <hip/hip_bf16.h>
#include <cstdint>
#include <cstddef>

typedef __attribute__((ext_vector_type(8))) short short8;
typedef __attribute__((ext_vector_type(4))) float f32x4;
typedef __attribute__((ext_vector_type(4))) unsigned uint4v;

#define LDS_AS __attribute__((address_space(3)))
#define GLB_AS __attribute__((address_space(1)))

__device__ __forceinline__ unsigned short f32_bf16(float f) {
  unsigned u = __builtin_bit_cast(unsigned, f);
  u += 0x7fffu + ((u >> 16) & 1u);
  return (unsigned short)(u >> 16);
}

__device__ __forceinline__ unsigned cvt_pk_bf16(float lo, float hi) {
  unsigned r;
  asm("v_cvt_pk_bf16_f32 %0, %1, %2" : "=v"(r) : "v"(lo), "v"(hi));
  return r;
}

// ---------------- convert f32 -> bf16, 4 elems/thread ----------------
__global__ __launch_bounds__(256) void k_cvt(const float* __restrict__ in,
                                             unsigned short* __restrict__ out, int n4) {
  int i = blockIdx.x * 256 + threadIdx.x;
  if (i >= n4) return;
  float4 v = reinterpret_cast<const float4*>(in)[i];
  ushort4 o;
  o.x = f32_bf16(v.x); o.y = f32_bf16(v.y); o.z = f32_bf16(v.z); o.w = f32_bf16(v.w);
  reinterpret_cast<ushort4*>(out)[i] = o;
}

// ---- fused convert+transpose for BOTH weights (round-16-verified) ----
__global__ __launch_bounds__(256) void k_cvt_t2(const float* __restrict__ wq,
                                                unsigned short* __restrict__ oq,
                                                const float* __restrict__ wo,
                                                unsigned short* __restrict__ oo) {
  __shared__ float t[32][33];
  int bx = blockIdx.x;
  const float* in;
  unsigned short* out;
  int C;
  if (bx < 96) { in = wq; out = oq; C = 3072; }
  else         { in = wo; out = oo; C = 1024; bx -= 96; }
  const int R = 1024;
  int c0 = bx * 32, r0 = blockIdx.y * 32;
  int lr = threadIdx.x & 31, lw = threadIdx.x >> 5;
#pragma unroll
  for (int i = 0; i < 32; i += 8)
    t[lw + i][lr] = in[(size_t)(r0 + lw + i) * C + c0 + lr];
  __syncthreads();
#pragma unroll
  for (int i = 0; i < 32; i += 8)
    out[(size_t)(c0 + lw + i) * R + r0 + lr] = f32_bf16(t[lr][lw + i]);
}

// ------ shared GEMM-BT mainloop (C = A * Bt^T), BK=64, XOR-swizzled LDS ------
// (round-14-verified)
__device__ __forceinline__ void gemm_bt_mainloop(
    const unsigned short* __restrict__ A, const unsigned short* __restrict__ Bt,
    int K, int m0, int n0, unsigned short* lds, int tid, f32x4 acc[4][4]) {
  const int w = tid >> 6, l = tid & 63;
  const int wr = w >> 1, wc = w & 1;
  const int lr = l & 15, lg = l >> 4;
  unsigned short* As = lds;         // [128][64] swizzled
  unsigned short* Bs = lds + 8192;  // [128][64] swizzled
  const int sslot = tid & 7;
  for (int kt = 0; kt < K; kt += 64) {
    __syncthreads();
#pragma unroll
    for (int i = 0; i < 4; ++i) {
      int idx = i * 256 + tid;
      int row = idx >> 3;
      int sw = sslot ^ (row & 7);
      __builtin_amdgcn_global_load_lds(
          (const GLB_AS unsigned int*)(A + (size_t)(m0 + row) * K + kt + sw * 8),
          (LDS_AS unsigned int*)(As + (size_t)idx * 8), 16, 0, 0);
    }
#pragma unroll
    for (int i = 0; i < 4; ++i) {
      int idx = i * 256 + tid;
      int row = idx >> 3;
      int sw = sslot ^ (row & 7);
      __builtin_amdgcn_global_load_lds(
          (const GLB_AS unsigned int*)(Bt + (size_t)(n0 + row) * K + kt + sw * 8),
          (LDS_AS unsigned int*)(Bs + (size_t)idx * 8), 16, 0, 0);
    }
    __syncthreads();
#pragma unroll
    for (int kc = 0; kc < 2; ++kc) {
      const int so = ((kc * 4 + lg) ^ (lr & 7)) * 8;  // frag row&7 == lr&7
      short8 a[4], b[4];
#pragma unroll
      for (int m = 0; m < 4; ++m)
        a[m] = *reinterpret_cast<const short8*>(As + (wr * 64 + m * 16 + lr) * 64 + so);
#pragma unroll
      for (int n = 0; n < 4; ++n)
        b[n] = *reinterpret_cast<const short8*>(Bs + (wc * 64 + n * 16 + lr) * 64 + so);
      __builtin_amdgcn_s_setprio(1);
#pragma unroll
      for (int m = 0; m < 4; ++m)
#pragma unroll
        for (int n = 0; n < 4; ++n)
          acc[m][n] = __builtin_amdgcn_mfma_f32_16x16x32_bf16(a[m], b[n], acc[m][n], 0, 0, 0);
      __builtin_amdgcn_s_setprio(0);
    }
  }
}

// ---------------- GEMM1: Zb(8192x1024) @ Wqkvt(3072x1024)^T -> Q,K,Vt ----------------
__global__ __launch_bounds__(256) void k_gemm_qkv(
    const unsigned short* __restrict__ Zb, const unsigned short* __restrict__ Wt,
    unsigned short* __restrict__ Qb, unsigned short* __restrict__ Kb,
    unsigned short* __restrict__ Vt) {
  __shared__ unsigned short lds[16384];
  f32x4 acc[4][4];
#pragma unroll
  for (int m = 0; m < 4; ++m)
#pragma unroll
    for (int n = 0; n < 4; ++n) acc[m][n] = (f32x4){0.f, 0.f, 0.f, 0.f};
  const int m0 = blockIdx.x * 128, n0 = blockIdx.y * 128;
  gemm_bt_mainloop(Zb, Wt, 1024, m0, n0, lds, threadIdx.x, acc);
  const int tid = threadIdx.x, w = tid >> 6, l = tid & 63;
  const int wr = w >> 1, wc = w & 1, lr = l & 15, lg = l >> 4;
#pragma unroll
  for (int n = 0; n < 4; ++n) {
    int gc = n0 + wc * 64 + n * 16;
    int part = gc >> 10;
    int within = gc & 1023;
    int h = within >> 6;
    int dhb = (within & 63) + lr;
#pragma unroll
    for (int m = 0; m < 4; ++m) {
      int gr = m0 + wr * 64 + m * 16 + lg * 4;
      int b = gr >> 11, pos = gr & 2047;
      size_t bh = (size_t)(b * 16 + h);
      if (part == 0) {
        unsigned short* dst = Qb + bh * (2048 * 64) + (size_t)pos * 64 + dhb;
#pragma unroll
        for (int r = 0; r < 4; ++r) dst[r * 64] = f32_bf16(acc[m][n][r]);
      } else if (part == 1) {
        unsigned short* dst = Kb + bh * (2048 * 64) + (size_t)pos * 64 + dhb;
#pragma unroll
        for (int r = 0; r < 4; ++r) dst[r * 64] = f32_bf16(acc[m][n][r]);
      } else {
        unsigned short* dst = Vt + bh * (64 * 2048) + (size_t)dhb * 2048 + pos;
        ushort4 pv;
        pv.x = f32_bf16(acc[m][n][0]); pv.y = f32_bf16(acc[m][n][1]);
        pv.z = f32_bf16(acc[m][n][2]); pv.w = f32_bf16(acc[m][n][3]);
        *reinterpret_cast<ushort4*>(dst) = pv;
      }
    }
  }
}

// -------- softmax + P-pack: packed-f32 (v_pk) max/fma/sum, defer-max THR=8 --------
// Value-equivalent to round-10-verified version up to fp summation order.
__device__ __forceinline__ void softmax_pack(f32x4 s[4], float& m_r, float& l_r,
                                             f32x4 o[4], short8 pb[2], bool lgodd,
                                             float cc) {
  f32x4 m01 = __builtin_elementwise_max(s[0], s[1]);
  f32x4 m23 = __builtin_elementwise_max(s[2], s[3]);
  f32x4 m4 = __builtin_elementwise_max(m01, m23);
  float tl = fmaxf(fmaxf(m4[0], m4[1]), fmaxf(m4[2], m4[3]));
  if (__any(tl > m_r + 8.0f)) {  // rare after early tiles
    float tm = fmaxf(tl, __shfl_xor(tl, 16));
    tm = fmaxf(tm, __shfl_xor(tm, 32));
    float mn = fmaxf(m_r, tm);
    float al = __builtin_amdgcn_exp2f((m_r - mn) * cc);
    m_r = mn;
    l_r *= al;
#pragma unroll
    for (int c = 0; c < 4; ++c)
#pragma unroll
      for (int r = 0; r < 4; ++r) o[c][r] *= al;
  }
  const float nb = m_r * cc;
  const f32x4 ccv = (f32x4){cc, cc, cc, cc};
  const f32x4 nbv = (f32x4){nb, nb, nb, nb};
#pragma unroll
  for (int c = 0; c < 4; ++c) {
    f32x4 t = s[c] * ccv - nbv;  // packed fma
#pragma unroll
    for (int r = 0; r < 4; ++r) s[c][r] = __builtin_amdgcn_exp2f(t[r]);
  }
  f32x4 sum4 = (s[0] + s[1]) + (s[2] + s[3]);  // packed adds
  float rs = (sum4[0] + sum4[1]) + (sum4[2] + sum4[3]);
  rs += __shfl_xor(rs, 16);
  rs += __shfl_xor(rs, 32);
  l_r += rs;
  unsigned Ap[4], Bp[4];
#pragma unroll
  for (int c = 0; c < 4; ++c) {
    Ap[c] = cvt_pk_bf16(s[c][0], s[c][1]);
    Bp[c] = cvt_pk_bf16(s[c][2], s[c][3]);
  }
#pragma unroll
  for (int kc = 0; kc < 2; ++kc) {
    unsigned ua = Ap[2 * kc], va = Ap[2 * kc + 1];
    asm("v_permlane32_swap_b32 %0, %1" : "+v"(ua), "+v"(va));
    unsigned uas = (unsigned)__shfl_xor((int)ua, 16);
    unsigned vas = (unsigned)__shfl_xor((int)va, 16);
    unsigned w0 = lgodd ? vas : ua;
    unsigned w2 = lgodd ? va : uas;
    unsigned ub = Bp[2 * kc], vb = Bp[2 * kc + 1];
    asm("v_permlane32_swap_b32 %0, %1" : "+v"(ub), "+v"(vb));
    unsigned ubs = (unsigned)__shfl_xor((int)ub, 16);
    unsigned vbs = (unsigned)__shfl_xor((int)vb, 16);
    unsigned w1 = lgodd ? vbs : ub;
    unsigned w3 = lgodd ? vb : ubs;
    uint4v pw = (uint4v){w0, w1, w2, w3};
    pb[kc] = __builtin_bit_cast(short8, pw);
  }
}

// ------- flash attention v10: v9 structure + packed-f32 softmax -------------------
__global__ __launch_bounds__(512, 4) void k_attn(
    const unsigned short* __restrict__ Q, const unsigned short* __restrict__ Kb,
    const unsigned short* __restrict__ Vt, unsigned short* __restrict__ O) {
  __shared__ unsigned short lds[32768];  // [2 buf][K 8192 | V 8192] shorts = 64 KB
  const int tid = threadIdx.x, w = tid >> 6, l = tid & 63;
  const int lr = l & 15, lg = l >> 4;
  const bool lgodd = (lg & 1) != 0;
  // XCD-aware remap (verified): 8 q-blocks of one (b,h) share wg&7 -> same XCD.
  const int wg = blockIdx.x;
  const int xcd = wg & 7, local = wg >> 3;
  const int bh = xcd + ((local >> 3) << 3);
  const int qb = local & 7;
  const unsigned short* Qp = Q + (size_t)bh * (2048 * 64);
  const unsigned short* Kp = Kb + (size_t)bh * (2048 * 64);
  const unsigned short* Vp = Vt + (size_t)bh * (64 * 2048);
  const int q0 = qb * 256 + w * 32;

  short8 aq[2][2];
#pragma unroll
  for (int g = 0; g < 2; ++g)
#pragma unroll
    for (int kc = 0; kc < 2; ++kc)
      aq[g][kc] = *reinterpret_cast<const short8*>(
          Qp + (size_t)(q0 + g * 16 + lr) * 64 + kc * 32 + lg * 8);

  float m0r = -3e38f, l0r = 0.f, m1r = -3e38f, l1r = 0.f;
  f32x4 o0[4], o1[4];
#pragma unroll
  for (int c = 0; c < 4; ++c) {
    o0[c] = (f32x4){0.f, 0.f, 0.f, 0.f};
    o1[c] = (f32x4){0.f, 0.f, 0.f, 0.f};
  }
  const f32x4 zero4 = (f32x4){0.f, 0.f, 0.f, 0.f};
  const float cc = 0.125f * 1.44269504089f;  // SCALE * log2(e)

  // loop-invariant swizzle offsets: frag row&7 == lr&7 (c*16 = 0 mod 8)
  const int so0 = (lg ^ (lr & 7)) * 8;
  const int so1 = ((4 + lg) ^ (lr & 7)) * 8;

  // staging: per epoch, K 128 rows (2 chunks/thread) + V 2 sub-tiles (2 chunks)
  const int srow = tid >> 3, sslot = tid & 7;
  const int ssw = sslot ^ (srow & 7);  // srow&7 == row&7 for both K halves (64%8==0)
#define STAGE_KV(bufK, bufV, kv0)                                                     \
  {                                                                                   \
    _Pragma("unroll")                                                                 \
    for (int s = 0; s < 2; ++s) {                                                     \
      __builtin_amdgcn_global_load_lds(                                               \
          (const GLB_AS unsigned int*)(Kp + (size_t)((kv0) + s * 64 + srow) * 64 +    \
                                       ssw * 8),                                      \
          (LDS_AS unsigned int*)((bufK) + (s * 512 + tid) * 8), 16, 0, 0);            \
      __builtin_amdgcn_global_load_lds(                                               \
          (const GLB_AS unsigned int*)(Vp + (size_t)srow * 2048 + (kv0) + s * 64 +    \
                                       ssw * 8),                                      \
          (LDS_AS unsigned int*)((bufV) + (s * 4096 + tid * 8)), 16, 0, 0);           \
    }                                                                                 \
  }

  unsigned short* K0 = lds;              // [128][64] (two 64-row sub-tiles)
  unsigned short* V0 = lds + 8192;       // two [64][64] sub-tiles
  unsigned short* K1 = lds + 16384;
  unsigned short* V1 = lds + 24576;

  STAGE_KV(K0, V0, 0);
  __syncthreads();

  for (int t = 0; t < 16; ++t) {
    unsigned short* Ks = (t & 1) ? K1 : K0;
    unsigned short* Vs = (t & 1) ? V1 : V0;
    if (t < 15) {
      unsigned short* Kn = (t & 1) ? K0 : K1;
      unsigned short* Vn = (t & 1) ? V0 : V1;
      STAGE_KV(Kn, Vn, (t + 1) * 128);
    }
#pragma unroll
    for (int sub = 0; sub < 2; ++sub) {
      const unsigned short* Kt = Ks + sub * 4096;
      const unsigned short* Vb = Vs + sub * 4096;
      f32x4 s0[4], s1[4];
      __builtin_amdgcn_s_setprio(1);
#pragma unroll
      for (int c = 0; c < 4; ++c) {
        const unsigned short* kb = Kt + c * 1024 + lr * 64;
        short8 ak0 = *reinterpret_cast<const short8*>(kb + so0);
        short8 ak1 = *reinterpret_cast<const short8*>(kb + so1);
        s0[c] = __builtin_amdgcn_mfma_f32_16x16x32_bf16(ak0, aq[0][0], zero4, 0, 0, 0);
        s1[c] = __builtin_amdgcn_mfma_f32_16x16x32_bf16(ak0, aq[1][0], zero4, 0, 0, 0);
        s0[c] = __builtin_amdgcn_mfma_f32_16x16x32_bf16(ak1, aq[0][1], s0[c], 0, 0, 0);
        s1[c] = __builtin_amdgcn_mfma_f32_16x16x32_bf16(ak1, aq[1][1], s1[c], 0, 0, 0);
      }
      __builtin_amdgcn_s_setprio(0);
      short8 pb0[2], pb1[2];
      softmax_pack(s0, m0r, l0r, o0, pb0, lgodd, cc);
      softmax_pack(s1, m1r, l1r, o1, pb1, lgodd, cc);
      __builtin_amdgcn_s_setprio(1);
#pragma unroll
      for (int c = 0; c < 4; ++c) {
        const unsigned short* vb = Vb + c * 1024 + lr * 64;
        short8 av0 = *reinterpret_cast<const short8*>(vb + so0);
        short8 av1 = *reinterpret_cast<const short8*>(vb + so1);
        o0[c] = __builtin_amdgcn_mfma_f32_16x16x32_bf16(av0, pb0[0], o0[c], 0, 0, 0);
        o1[c] = __builtin_amdgcn_mfma_f32_16x16x32_bf16(av0, pb1[0], o1[c], 0, 0, 0);
        o0[c] = __builtin_amdgcn_mfma_f32_16x16x32_bf16(av1, pb0[1], o0[c], 0, 0, 0);
        o1[c] = __builtin_amdgcn_mfma_f32_16x16x32_bf16(av1, pb1[1], o1[c], 0, 0, 0);
      }
      __builtin_amdgcn_s_setprio(0);
    }
    __syncthreads();
  }

  const int b = bh >> 4, h = bh & 15;
#pragma unroll
  for (int g = 0; g < 2; ++g) {
    const float inv = 1.0f / (g ? l1r : l0r);
    const f32x4* o = g ? o1 : o0;
    const size_t row = (size_t)b * 2048 + q0 + g * 16 + lr;
#pragma unroll
    for (int c = 0; c < 4; ++c) {
      ushort4 pv;
      pv.x = f32_bf16(o[c][0] * inv);
      pv.y = f32_bf16(o[c][1] * inv);
      pv.z = f32_bf16(o[c][2] * inv);
      pv.w = f32_bf16(o[c][3] * inv);
      *reinterpret_cast<ushort4*>(const_cast<unsigned short*>(
          O + row * 1024 + h * 64 + c * 16 + lg * 4)) = pv;
    }
  }
#undef STAGE_KV
}

// ---------------- GEMM2: Ob(8192x1024) @ Woutt(1024x1024)^T + b -> out f32 ----------------
__global__ __launch_bounds__(256) void k_gemm_out(
    const unsigned short* __restrict__ Ob, const unsigned short* __restrict__ Wt,
    const float* __restrict__ bias, float* __restrict__ out) {
  __shared__ unsigned short lds[16384];
  f32x4 acc[4][4];
#pragma unroll
  for (int m = 0; m < 4; ++m)
#pragma unroll
    for (int n = 0; n < 4; ++n) acc[m][n] = (f32x4){0.f, 0.f, 0.f, 0.f};
  const int m0 = blockIdx.x * 128, n0 = blockIdx.y * 128;
  gemm_bt_mainloop(Ob, Wt, 1024, m0, n0, lds, threadIdx.x, acc);
  const int tid = threadIdx.x, w = tid >> 6, l = tid & 63;
  const int wr = w >> 1, wc = w & 1, lr = l & 15, lg = l >> 4;
#pragma unroll
  for (int n = 0; n < 4; ++n) {
    int gc = n0 + wc * 64 + n * 16 + lr;
    float bo = bias[gc];
#pragma unroll
    for (int m = 0; m < 4; ++m) {
      int gr = m0 + wr * 64 + m * 16 + lg * 4;
#pragma unroll
      for (int r = 0; r < 4; ++r)
        out[(size_t)(gr + r) * 1024 + gc] = acc[m][n][r] + bo;
    }
  }
}

extern "C" void kernel_launch(void* const* d_in, const int* in_sizes, int n_in,
                              void* d_out, int out_size, void* d_ws, size_t ws_size,
                              hipStream_t stream) {
  const float* z     = (const float*)d_in[0];
  const float* w_qkv = (const float*)d_in[1];
  const float* w_out = (const float*)d_in[2];
  const float* b_out = (const float*)d_in[3];
  float* out = (float*)d_out;

  unsigned short* ws = (unsigned short*)d_ws;
  unsigned short* Zb    = ws;              // 8192*1024      (reused as Ob after GEMM1)
  unsigned short* Wqkvt = ws + 8388608;    // 3072*1024
  unsigned short* Woutt = ws + 11534336;   // 1024*1024
  unsigned short* Qb    = ws + 12582912;   // B*H*N*DH
  unsigned short* Kb    = ws + 20971520;
  unsigned short* Vt    = ws + 29360128;
  unsigned short* Ob    = Zb;              // alias: Zb dead after GEMM1 (stream-ordered)

  k_cvt<<<dim3(8192), dim3(256), 0, stream>>>(z, Zb, 2097152);
  k_cvt_t2<<<dim3(128, 32), dim3(256), 0, stream>>>(w_qkv, Wqkvt, w_out, Woutt);
  k_gemm_qkv<<<dim3(64, 24), dim3(256), 0, stream>>>(Zb, Wqkvt, Qb, Kb, Vt);
  k_attn<<<dim3(512), dim3(512), 0, stream>>>(Qb, Kb, Vt, Ob);
  k_gemm_out<<<dim3(64, 8), dim3(256), 0, stream>>>(Ob, Woutt, b_out, out);
}